// Round 10
// baseline (1464.172 us; speedup 1.0000x reference)
//
#include <hip/hip_runtime.h>
#include <hip/hip_fp16.h>
#include <math.h>

#define N_USERS 50000
#define N_ITEMS 30000
#define NNODES  80000
#define NHALF   40000
#define NEDGES  640000
#define NCLUS   64
#define NEG     0.2f
#define EPSV    1e-5f

typedef __attribute__((ext_vector_type(8))) short bf16x8;
typedef __attribute__((ext_vector_type(4))) float f32x4;

__device__ __forceinline__ float lrelu(float x){ return x > 0.f ? x : NEG*x; }

__device__ __forceinline__ unsigned short f2bf(float f){
  unsigned u = __float_as_uint(f);
  u += 0x7fffu + ((u>>16)&1u);
  return (unsigned short)(u>>16);
}
__device__ __forceinline__ unsigned pk2(float lo, float hi){
  return (unsigned)f2bf(lo) | ((unsigned)f2bf(hi) << 16);
}
__device__ __forceinline__ float4 f4add(float4 a, float4 b){
  return make_float4(a.x+b.x, a.y+b.y, a.z+b.z, a.w+b.w);
}

// ---------------- phase 0: pair histogram (LDS-aggregated, 1024-thread blocks) ----------------
__global__ __launch_bounds__(1024) void k_pairhist(
    const int* __restrict__ ei, const float* __restrict__ eattr, const int* __restrict__ clus,
    int* __restrict__ cnt, int* __restrict__ intra,
    float* __restrict__ pcb, float* __restrict__ pa0b, float* __restrict__ pa1b)
{
  __shared__ float pc[4096];
  __shared__ float pa0[4096];
  __shared__ float pa1[4096];
  for (int i=threadIdx.x; i<4096; i+=1024){ pc[i]=0.f; pa0[i]=0.f; pa1[i]=0.f; }
  __syncthreads();
  for (int e = blockIdx.x*1024 + threadIdx.x; e < NEDGES; e += 128*1024){
    int s = ei[e], d = ei[NEDGES+e];
    int cu = clus[s], cv = clus[d];
    atomicAdd(&cnt[d], 1);
    if (cu == cv) { atomicAdd(&intra[d], 1); }
    else {
      float2 a = *reinterpret_cast<const float2*>(&eattr[2*e]);
      int k = cu*NCLUS + cv;
      atomicAdd(&pc[k], 1.f);
      atomicAdd(&pa0[k], a.x);
      atomicAdd(&pa1[k], a.y);
    }
  }
  __syncthreads();
  int b = blockIdx.x;
  for (int i=threadIdx.x; i<4096; i+=1024){
    pcb [i*128 + b] = pc[i];
    pa0b[i*128 + b] = pa0[i];
    pa1b[i*128 + b] = pa1[i];
  }
}

__global__ __launch_bounds__(64) void k_pairreduce(
    const float* __restrict__ pcb, const float* __restrict__ pa0b, const float* __restrict__ pa1b,
    float* __restrict__ pair_cnt, float* __restrict__ avg_attr)
{
  int i = blockIdx.x*64 + threadIdx.x;  // 4096 total over grid 64
  float c=0.f, s0=0.f, s1=0.f;
  const float4* P0 = (const float4*)(pcb  + (size_t)i*128);
  const float4* P1 = (const float4*)(pa0b + (size_t)i*128);
  const float4* P2 = (const float4*)(pa1b + (size_t)i*128);
  for (int b=0;b<32;b++){
    float4 v0=P0[b], v1=P1[b], v2=P2[b];
    c  += v0.x+v0.y+v0.z+v0.w;
    s0 += v1.x+v1.y+v1.z+v1.w;
    s1 += v2.x+v2.y+v2.z+v2.w;
  }
  pair_cnt[i] = c;
  float inv = 1.f/fmaxf(c, 1.f);
  avg_attr[2*i]   = s0*inv;
  avg_attr[2*i+1] = s1*inv;
}

// scan block (+ optional node histogram)
__global__ __launch_bounds__(256) void k_scan_block(const int* __restrict__ in, int* __restrict__ out,
                                                    int* __restrict__ bsum, int n,
                                                    const int* __restrict__ clus, int* __restrict__ csize){
  __shared__ int buf[256];
  int i = blockIdx.x*256 + threadIdx.x;
  int v = (i < n) ? in[i] : 0;
  if (csize && i < n) atomicAdd(&csize[clus[i]], 1);
  buf[threadIdx.x] = v; __syncthreads();
  for (int off=1; off<256; off<<=1){
    int t = (threadIdx.x>=off) ? buf[threadIdx.x-off] : 0;
    __syncthreads();
    buf[threadIdx.x] += t;
    __syncthreads();
  }
  if (i < n) out[i] = buf[threadIdx.x] - v;
  if (threadIdx.x == 255) bsum[blockIdx.x] = buf[255];
}

__global__ __launch_bounds__(512) void k_scan_bsum(int* __restrict__ bsum, int nb){
  __shared__ int buf[512];
  int v = (threadIdx.x < nb) ? bsum[threadIdx.x] : 0;
  buf[threadIdx.x] = v; __syncthreads();
  for (int off=1; off<512; off<<=1){
    int t = (threadIdx.x>=off) ? buf[threadIdx.x-off] : 0;
    __syncthreads();
    buf[threadIdx.x] += t;
    __syncthreads();
  }
  if (threadIdx.x < nb) bsum[threadIdx.x] = buf[threadIdx.x] - v;
}

__global__ __launch_bounds__(256) void k_scan_add(int* __restrict__ out, const int* __restrict__ bsum,
                                                  int n, int total){
  int i = blockIdx.x*256 + threadIdx.x;
  if (i < n) out[i] += bsum[i>>8];
  if (i == 0) out[n] = total;
}

// fill main CSR + intra CSR + la (loop-attr sums), all in one pass
__global__ __launch_bounds__(256) void k_fill_csr(const int* __restrict__ ei, const float* __restrict__ eattr,
                                                  const int* __restrict__ clus,
                                                  const int* __restrict__ offs, const int* __restrict__ ioffs,
                                                  int* __restrict__ cursor, int* __restrict__ cursor2,
                                                  int2* __restrict__ csr, int* __restrict__ csr2,
                                                  float* __restrict__ la){
  int e = blockIdx.x*256 + threadIdx.x;
  if (e >= NEDGES) return;
  int s = ei[e], d = ei[NEDGES+e];
  int pos = offs[d] + atomicAdd(&cursor[d], 1);
  csr[pos] = make_int2(s, e);
  float2 a = *reinterpret_cast<const float2*>(&eattr[2*e]);
  atomicAdd(&la[2*d],   a.x);
  atomicAdd(&la[2*d+1], a.y);
  if (clus[s] == clus[d]){
    int p2 = ioffs[d] + atomicAdd(&cursor2[d], 1);
    csr2[p2] = s;
  }
}

// ---------------- all weight transposes+converts in one kernel ----------------
__global__ __launch_bounds__(256) void k_wtall(const float* __restrict__ W1, const float* __restrict__ W2,
                       const float* __restrict__ gcnW, const float* __restrict__ gat_lin,
                       unsigned short* __restrict__ W1t, unsigned short* __restrict__ W2t,
                       unsigned short* __restrict__ gcnWt, unsigned short* __restrict__ glt){
  int i = blockIdx.x*256 + threadIdx.x;
  if (i < 229376){            // W1: K=896, N=256
    int n = i/896, k = i - n*896;
    W1t[i] = f2bf(W1[(size_t)k*256 + n]);
  } else if (i < 262144){     // W2: K=256, N=128
    int j = i - 229376; int n = j/256, k = j - n*256;
    W2t[j] = f2bf(W2[(size_t)k*128 + n]);
  } else if (i < 278528){     // gcnW: 128x128
    int j = i - 262144; int n = j/128, k = j - n*128;
    gcnWt[j] = f2bf(gcnW[(size_t)k*128 + n]);
  } else if (i < 475136){     // gat_lin: 3 x (K=128, N=512)
    int j = i - 278528; int l = j >> 16; int r = j & 65535; int n = r/128, k = r - n*128;
    glt[j] = f2bf(gat_lin[(size_t)l*65536 + (size_t)k*512 + n]);
  }
}

// ---------------- bf16 MFMA GEMM: C = act(A @ Bt^T + bias) ----------------
// AF32: A is f32 (converted during staging); CONCAT: A|A2 split at K1.
// OUT: 0=f32, 1=bf16, 2=f16
// ASD: also emit a_s/a_d per-row dots with attS/attD (blockIdx.y = head).
template<int AF32, int CONCAT, int OUT, int RELU, int BIAS, int ASD>
__global__ __launch_bounds__(256)
void k_mgemm(const void* __restrict__ Av, const float* __restrict__ A2,
             const unsigned short* __restrict__ Bt, const float* __restrict__ bias,
             void* __restrict__ Cv, int M, int N, int K, int K1,
             const float* __restrict__ attS, const float* __restrict__ attD,
             float* __restrict__ oas, float* __restrict__ oad)
{
  __shared__ unsigned short As[128*64];
  __shared__ unsigned short Bs[128*64];
  __shared__ float sAs[2][128], sAd[2][128];
  const int tid = threadIdx.x;
  const int lane = tid & 63, w = tid >> 6;
  const int row0 = blockIdx.x*128, col0 = blockIdx.y*128;
  const int wm = w >> 1, wn = w & 1;
  const int l15 = lane & 15, l4 = lane >> 4;
  f32x4 acc[4][4];
  #pragma unroll
  for (int i=0;i<4;i++)
    #pragma unroll
    for (int n=0;n<4;n++) acc[i][n] = (f32x4){0.f,0.f,0.f,0.f};

  const int rr0 = w*32 + (lane>>3);
  const int cA = lane & 7;

  for (int kt = 0; kt < K; kt += 64){
    uint4 ra[4], rb[4];
    #pragma unroll
    for (int i=0;i<4;i++){
      int rr = rr0 + i*8;
      int ga = row0 + rr; ga = (ga < M) ? ga : (M-1);
      int gb = col0 + rr; gb = (gb < N) ? gb : (N-1);
      int gk = kt + cA*8;
      if (AF32){
        const float* Af = (const float*)Av;
        const float* src;
        if (CONCAT && gk >= K1) src = A2 + (size_t)ga*(K-K1) + (gk - K1);
        else                    src = Af + (size_t)ga*(CONCAT ? K1 : K) + gk;
        float4 f0 = ((const float4*)src)[0];
        float4 f1 = ((const float4*)src)[1];
        ra[i] = make_uint4(pk2(f0.x,f0.y), pk2(f0.z,f0.w), pk2(f1.x,f1.y), pk2(f1.z,f1.w));
      } else {
        ra[i] = *reinterpret_cast<const uint4*>((const unsigned short*)Av + (size_t)ga*K + gk);
      }
      rb[i] = *reinterpret_cast<const uint4*>(Bt + (size_t)gb*K + gk);
    }
    __syncthreads();
    #pragma unroll
    for (int i=0;i<4;i++){
      int rr = rr0 + i*8;
      int ch = cA ^ (rr & 7);
      *reinterpret_cast<uint4*>(&As[rr*64 + ch*8]) = ra[i];
      *reinterpret_cast<uint4*>(&Bs[rr*64 + ch*8]) = rb[i];
    }
    __syncthreads();
    #pragma unroll
    for (int k0=0;k0<2;k0++){
      bf16x8 af[4], bff[4];
      #pragma unroll
      for (int i=0;i<4;i++){
        int row = wm*64 + i*16 + l15;
        int ch = (k0*4 + l4) ^ (row & 7);
        af[i] = *reinterpret_cast<const bf16x8*>(&As[row*64 + ch*8]);
      }
      #pragma unroll
      for (int n=0;n<4;n++){
        int row = wn*64 + n*16 + l15;
        int ch = (k0*4 + l4) ^ (row & 7);
        bff[n] = *reinterpret_cast<const bf16x8*>(&Bs[row*64 + ch*8]);
      }
      #pragma unroll
      for (int i=0;i<4;i++)
        #pragma unroll
        for (int n=0;n<4;n++)
          acc[i][n] = __builtin_amdgcn_mfma_f32_16x16x32_bf16(af[i], bff[n], acc[i][n], 0, 0, 0);
    }
  }
  // C store
  #pragma unroll
  for (int i=0;i<4;i++){
    int rowb = row0 + wm*64 + i*16 + l4*4;
    #pragma unroll
    for (int n=0;n<4;n++){
      int col = col0 + wn*64 + n*16 + l15;
      float bv = BIAS ? bias[col] : 0.f;
      #pragma unroll
      for (int r=0;r<4;r++){
        int row = rowb + r;
        if (row < M){
          float y = acc[i][n][r] + bv;
          if (RELU) y = fmaxf(y, 0.f);
          if (OUT == 1)      ((unsigned short*)Cv)[(size_t)row*N + col] = f2bf(y);
          else if (OUT == 2) ((__half*)Cv)[(size_t)row*N + col] = __float2half(y);
          else               ((float*)Cv)[(size_t)row*N + col] = y;
        }
      }
    }
  }
  if (ASD){
    const float* aSb = attS + (size_t)blockIdx.y*128;
    const float* aDb = attD + (size_t)blockIdx.y*128;
    float aS[4], aD[4];
    #pragma unroll
    for (int n=0;n<4;n++){
      int c = wn*64 + n*16 + l15;
      aS[n] = aSb[c]; aD[n] = aDb[c];
    }
    float ps[4][4], pd[4][4];
    #pragma unroll
    for (int i=0;i<4;i++)
      #pragma unroll
      for (int r=0;r<4;r++){
        float s=0.f, d=0.f;
        #pragma unroll
        for (int n=0;n<4;n++){
          s = fmaf(acc[i][n][r], aS[n], s);
          d = fmaf(acc[i][n][r], aD[n], d);
        }
        ps[i][r]=s; pd[i][r]=d;
      }
    #pragma unroll
    for (int m=1;m<16;m<<=1){
      #pragma unroll
      for (int i=0;i<4;i++)
        #pragma unroll
        for (int r=0;r<4;r++){
          ps[i][r] += __shfl_xor(ps[i][r], m);
          pd[i][r] += __shfl_xor(pd[i][r], m);
        }
    }
    if (l15 == 0){
      #pragma unroll
      for (int i=0;i<4;i++)
        #pragma unroll
        for (int r=0;r<4;r++){
          int rl = wm*64 + i*16 + l4*4 + r;
          sAs[wn][rl] = ps[i][r];
          sAd[wn][rl] = pd[i][r];
        }
    }
    __syncthreads();
    if (tid < 128){
      int row = row0 + tid;
      if (row < M){
        int head = blockIdx.y;
        oas[(size_t)row*4 + head] = sAs[0][tid] + sAs[1][tid];
        oad[(size_t)row*4 + head] = sAd[0][tid] + sAd[1][tid];
      }
    }
  }
}

// ---------------- f32 SGEMM (tiny pooled GEMM only) ----------------
template<int CONCAT, int ACT>
__global__ __launch_bounds__(256)
void k_sgemm(const float* __restrict__ A, const float* __restrict__ A2,
             const float* __restrict__ B, const float* __restrict__ bias,
             float* __restrict__ C, int M, int N, int K, int K1)
{
  __shared__ float As[8][128];
  __shared__ float Bs[8][128];
  int row0 = blockIdx.x*128, col0 = blockIdx.y*128;
  int tid = threadIdx.x;
  int tx = tid & 15, ty = tid >> 4;
  float acc[8][8];
  #pragma unroll
  for (int i=0;i<8;i++)
    #pragma unroll
    for (int j=0;j<8;j++) acc[i][j]=0.f;

  int arow = tid >> 1, acol = (tid & 1)*4;
  int brow = tid >> 5, bcol = (tid & 31)*4;
  int K2 = K - K1;

  for (int k0=0; k0<K; k0+=8){
    float4 av = make_float4(0.f,0.f,0.f,0.f);
    int gr = row0 + arow, gk = k0 + acol;
    if (gr < M){
      if (CONCAT){
        if (gk < K1) av = *reinterpret_cast<const float4*>(&A [(size_t)gr*K1 + gk]);
        else         av = *reinterpret_cast<const float4*>(&A2[(size_t)gr*K2 + (gk-K1)]);
      } else {
        av = *reinterpret_cast<const float4*>(&A[(size_t)gr*K + gk]);
      }
    }
    As[acol+0][arow]=av.x; As[acol+1][arow]=av.y; As[acol+2][arow]=av.z; As[acol+3][arow]=av.w;
    float4 bv = *reinterpret_cast<const float4*>(&B[(size_t)(k0+brow)*N + col0 + bcol]);
    *reinterpret_cast<float4*>(&Bs[brow][bcol]) = bv;
    __syncthreads();
    #pragma unroll
    for (int kk=0; kk<8; ++kk){
      float a[8], b[8];
      *(float4*)&a[0] = *(float4*)&As[kk][ty*8];
      *(float4*)&a[4] = *(float4*)&As[kk][ty*8+4];
      *(float4*)&b[0] = *(float4*)&Bs[kk][tx*8];
      *(float4*)&b[4] = *(float4*)&Bs[kk][tx*8+4];
      #pragma unroll
      for (int i=0;i<8;i++)
        #pragma unroll
        for (int j=0;j<8;j++) acc[i][j] = fmaf(a[i], b[j], acc[i][j]);
    }
    __syncthreads();
  }
  #pragma unroll
  for (int i=0;i<8;i++){
    int r = row0 + ty*8 + i;
    if (r >= M) continue;
    #pragma unroll
    for (int j4=0;j4<2;j4++){
      int c = col0 + tx*8 + j4*4;
      float4 v = make_float4(acc[i][j4*4], acc[i][j4*4+1], acc[i][j4*4+2], acc[i][j4*4+3]);
      if (bias){
        float4 bb = *reinterpret_cast<const float4*>(&bias[c]);
        v = f4add(v, bb);
      }
      if (ACT == 1){
        v.x=fmaxf(v.x,0.f); v.y=fmaxf(v.y,0.f); v.z=fmaxf(v.z,0.f); v.w=fmaxf(v.w,0.f);
      }
      *reinterpret_cast<float4*>(&C[(size_t)r*N + c]) = v;
    }
  }
}

// ---------------- GCN aggregation (intra-CSR: only intra-cluster edges) ----------------
__global__ __launch_bounds__(256) void k_gcn(const unsigned short* __restrict__ XWh, const int* __restrict__ ioffs,
                      const int* __restrict__ csr2, const int* __restrict__ intra,
                      const float* __restrict__ gcn_b, float* __restrict__ Xc)
{
  int wid  = (blockIdx.x*blockDim.x + threadIdx.x) >> 6;
  int lane = threadIdx.x & 63;
  int nw   = (gridDim.x*blockDim.x) >> 6;
  for (int n = wid; n < NNODES; n += nw){
    int cntn = intra[n];
    float deg = 1.f + (float)cntn;
    float dinv_n = rsqrtf(deg);
    __half2 hx = *reinterpret_cast<const __half2*>(XWh + (size_t)n*128 + lane*2);
    float2 acc;
    acc.x = __low2float(hx)/deg; acc.y = __high2float(hx)/deg;
    int io0 = ioffs[n];
    for (int j=0; j<cntn; ++j){
      int s = csr2[io0+j];
      float w = dinv_n * rsqrtf(1.f + (float)intra[s]);
      __half2 hs = *reinterpret_cast<const __half2*>(XWh + (size_t)s*128 + lane*2);
      acc.x = fmaf(w, __low2float(hs), acc.x);
      acc.y = fmaf(w, __high2float(hs), acc.y);
    }
    float2 bb = *reinterpret_cast<const float2*>(&gcn_b[lane*2]);
    acc.x += bb.x; acc.y += bb.y;
    *reinterpret_cast<float2*>(&Xc[(size_t)n*128 + lane*2]) = acc;
  }
}

// ---------------- cluster pooling: LDS partials + reduce ----------------
__global__ __launch_bounds__(256) void k_pool1(const float* __restrict__ Xc, const int* __restrict__ clus,
                                               float* __restrict__ part){
  __shared__ float lp[8192];
  for (int i=threadIdx.x; i<8192; i+=256) lp[i]=0.f;
  __syncthreads();
  int d = threadIdx.x & 127, rg = threadIdx.x >> 7;
  int n0 = blockIdx.x*200;
  for (int n = n0+rg; n < n0+200; n += 2){
    int c = clus[n];
    atomicAdd(&lp[c*128 + d], Xc[(size_t)n*128 + d]);
  }
  __syncthreads();
  for (int i=threadIdx.x; i<8192; i+=256) part[(size_t)blockIdx.x*8192 + i] = lp[i];
}
__global__ __launch_bounds__(256) void k_pool2(const float* __restrict__ part, const int* __restrict__ csize,
                                               float* __restrict__ pooled){
  int i = blockIdx.x*256 + threadIdx.x; // 8192
  float s = 0.f;
  for (int b=0;b<400;b++) s += part[(size_t)b*8192 + i];
  pooled[i] = s / fmaxf((float)csize[i>>7], 1.f);
}

// ---------------- small precomputes ----------------
__global__ __launch_bounds__(64) void k_m2(const float* __restrict__ g_lin_e, const float* __restrict__ g_att_e,
                    const float* __restrict__ gat_lin_e, const float* __restrict__ gat_att_e,
                    float* __restrict__ M2g, float* __restrict__ M2){
  int t = threadIdx.x;
  if (t < 8){
    int j = t >> 2, h = t & 3;
    float s = 0.f;
    for (int c=0;c<128;c++) s += g_lin_e[j*512 + h*128 + c] * g_att_e[h*128 + c];
    M2g[j*4+h] = s;
  } else if (t < 32){
    int u = t - 8; int l = u >> 3, j = (u >> 2) & 1, h = u & 3;
    float s = 0.f;
    for (int c=0;c<128;c++) s += gat_lin_e[l*1024 + j*512 + h*128 + c] * gat_att_e[l*512 + h*128 + c];
    M2[l*8 + j*4 + h] = s;
  }
}

// ---------------- cluster GAT (tiny) ----------------
__global__ __launch_bounds__(64) void k_loop_c(const float* __restrict__ pair_cnt, const float* __restrict__ avg_attr,
                                               float* __restrict__ loop_c){
  int d = threadIdx.x;
  if (d >= NCLUS) return;
  float ic=0.f, l0=0.f, l1=0.f;
  for (int s=0;s<NCLUS;s++){
    int k = s*NCLUS + d;
    if (pair_cnt[k] > 0.f){ ic += 1.f; l0 += avg_attr[2*k]; l1 += avg_attr[2*k+1]; }
  }
  float inv = 1.f / fmaxf(ic, 1.f);
  loop_c[2*d] = l0*inv; loop_c[2*d+1] = l1*inv;
}
__global__ __launch_bounds__(256) void k_asc(const float* __restrict__ xh_c,
                     const float* __restrict__ g_att_s, const float* __restrict__ g_att_d,
                     float* __restrict__ a_s_c, float* __restrict__ a_d_c){
  int t = threadIdx.x;
  int s = t >> 2, h = t & 3;
  float ss=0.f, sd=0.f;
  for (int c=0;c<128;c++){
    float x = xh_c[s*512 + h*128 + c];
    ss += x * g_att_s[h*128 + c];
    sd += x * g_att_d[h*128 + c];
  }
  a_s_c[s*4+h] = ss; a_d_c[s*4+h] = sd;
}
__global__ __launch_bounds__(128) void k_clout(const float* __restrict__ a_s_c, const float* __restrict__ a_d_c,
                       const float* __restrict__ loop_c, const float* __restrict__ M2g,
                       const float* __restrict__ pair_cnt, const float* __restrict__ avg_attr,
                       const float* __restrict__ xh_c, const float* __restrict__ g_bias,
                       float* __restrict__ cl_out)
{
  int d = blockIdx.x;
  __shared__ float p[NCLUS*4];
  int t = threadIdx.x;
  if (t < NCLUS){
    int s = t;
    for (int h=0; h<4; ++h){
      float v;
      if (s == d){
        v = lrelu(a_s_c[d*4+h] + a_d_c[d*4+h] + loop_c[2*d]*M2g[h] + loop_c[2*d+1]*M2g[4+h]);
      } else if (pair_cnt[s*NCLUS+d] > 0.f){
        int k = s*NCLUS + d;
        v = lrelu(a_s_c[s*4+h] + a_d_c[d*4+h] + avg_attr[2*k]*M2g[h] + avg_attr[2*k+1]*M2g[4+h]);
      } else {
        v = -INFINITY;
      }
      p[s*4+h] = v;
    }
  }
  __syncthreads();
  if (t < 4){
    int h = t;
    float m = -INFINITY;
    for (int s=0;s<NCLUS;s++) m = fmaxf(m, p[s*4+h]);
    float sum = 0.f;
    for (int s=0;s<NCLUS;s++){
      float a = p[s*4+h];
      float e = (a == -INFINITY) ? 0.f : expf(a - m);
      p[s*4+h] = e; sum += e;
    }
    float inv = 1.f/sum;
    for (int s=0;s<NCLUS;s++) p[s*4+h] *= inv;
  }
  __syncthreads();
  int c = t;
  float acc = 0.f;
  for (int s=0;s<NCLUS;s++){
    #pragma unroll
    for (int h=0;h<4;h++) acc += p[s*4+h]*xh_c[s*512 + h*128 + c];
  }
  cl_out[d*128 + c] = 0.25f*acc + g_bias[c];
}

// Xcomb = Xc + cl_out[clus]; write bf16 only
__global__ __launch_bounds__(256) void k_xcomb(const float* __restrict__ Xc, const float* __restrict__ cl_out,
                                               const int* __restrict__ clus, unsigned short* __restrict__ outbf){
  int i = blockIdx.x*256 + threadIdx.x;
  int stride = gridDim.x*256;
  for (; i < NNODES*32; i += stride){
    int n = i >> 5, d4 = i & 31;
    float4 a = ((const float4*)Xc)[i];
    float4 b = ((const float4*)&cl_out[clus[n]*128])[d4];
    float4 r = f4add(a, b);
    uint2 u; u.x = pk2(r.x, r.y); u.y = pk2(r.z, r.w);
    ((uint2*)outbf)[i] = u;
  }
}

// ---------------- GAT edge aggregation (f16 xh, dual-node per wave, 2-deep each) ----------------
__global__ __launch_bounds__(256) void k_gat(const unsigned short* __restrict__ xh, const float* __restrict__ a_s,
                     const float* __restrict__ a_d, const float* __restrict__ eattr,
                     const int* __restrict__ offs, const int2* __restrict__ csr,
                     const float* __restrict__ la, const float* __restrict__ M2l,
                     const float* __restrict__ bias, __half* __restrict__ out)
{
  int wid  = (blockIdx.x*blockDim.x + threadIdx.x) >> 6;  // 0..NHALF-1
  int lane = threadIdx.x & 63;
  int h = lane >> 4;
  float m2a = M2l[h], m2b = M2l[4+h];
  int nA = wid, nB = wid + NHALF;

  int a0 = offs[nA], a1 = offs[nA+1];
  int b0 = offs[nB], b1 = offs[nB+1];
  int lenA = a1 - a0, lenB = b1 - b0;

  float adnA = a_d[nA*4+h], adnB = a_d[nB*4+h];
  float invA = 1.f/fmaxf((float)lenA, 1.f), invB = 1.f/fmaxf((float)lenB, 1.f);
  float plA = __expf(lrelu(a_s[nA*4+h] + adnA + la[2*nA]*invA*m2a + la[2*nA+1]*invA*m2b));
  float plB = __expf(lrelu(a_s[nB*4+h] + adnB + la[2*nB]*invB*m2a + la[2*nB+1]*invB*m2b));
  float denomA = plA, denomB = plB;

  uint4 uSA = *reinterpret_cast<const uint4*>(xh + (size_t)nA*512 + lane*8);
  uint4 uSB = *reinterpret_cast<const uint4*>(xh + (size_t)nB*512 + lane*8);
  __half2* xA = reinterpret_cast<__half2*>(&uSA);
  __half2* xB = reinterpret_cast<__half2*>(&uSB);
  __half2 plA2 = __float2half2_rn(plA), plB2 = __float2half2_rn(plB);
  __half2 accA0=__hmul2(xA[0],plA2), accA1=__hmul2(xA[1],plA2), accA2=__hmul2(xA[2],plA2), accA3=__hmul2(xA[3],plA2);
  __half2 accB0=__hmul2(xB[0],plB2), accB1=__hmul2(xB[1],plB2), accB2=__hmul2(xB[2],plB2), accB3=__hmul2(xB[3],plB2);

  int2 seA0=make_int2(0,0), seA1=make_int2(0,0), seB0=make_int2(0,0), seB1=make_int2(0,0);
  uint4 uA0=make_uint4(0,0,0,0), uA1=make_uint4(0,0,0,0), uB0=make_uint4(0,0,0,0), uB1=make_uint4(0,0,0,0);
  if (lenA > 0){ seA0 = csr[a0];   uA0 = *reinterpret_cast<const uint4*>(xh + (size_t)seA0.x*512 + lane*8); }
  if (lenB > 0){ seB0 = csr[b0];   uB0 = *reinterpret_cast<const uint4*>(xh + (size_t)seB0.x*512 + lane*8); }
  if (lenA > 1){ seA1 = csr[a0+1]; uA1 = *reinterpret_cast<const uint4*>(xh + (size_t)seA1.x*512 + lane*8); }
  if (lenB > 1){ seB1 = csr[b0+1]; uB1 = *reinterpret_cast<const uint4*>(xh + (size_t)seB1.x*512 + lane*8); }

  int len = lenA > lenB ? lenA : lenB;
  for (int i=0; i<len; ++i){
    if (i < lenA){
      int s = seA0.x, e = seA0.y; uint4 u = uA0;
      seA0 = seA1; uA0 = uA1;
      if (i+2 < lenA){ seA1 = csr[a0+i+2]; uA1 = *reinterpret_cast<const uint4*>(xh + (size_t)seA1.x*512 + lane*8); }
      float2 ea = *reinterpret_cast<const float2*>(&eattr[2*e]);
      float pe = __expf(lrelu(a_s[s*4+h] + adnA + ea.x*m2a + ea.y*m2b));
      denomA += pe;
      __half2 pe2 = __float2half2_rn(pe);
      __half2* y = reinterpret_cast<__half2*>(&u);
      accA0=__hfma2(y[0],pe2,accA0); accA1=__hfma2(y[1],pe2,accA1);
      accA2=__hfma2(y[2],pe2,accA2); accA3=__hfma2(y[3],pe2,accA3);
    }
    if (i < lenB){
      int s = seB0.x, e = seB0.y; uint4 u = uB0;
      seB0 = seB1; uB0 = uB1;
      if (i+2 < lenB){ seB1 = csr[b0+i+2]; uB1 = *reinterpret_cast<const uint4*>(xh + (size_t)seB1.x*512 + lane*8); }
      float2 ea = *reinterpret_cast<const float2*>(&eattr[2*e]);
      float pe = __expf(lrelu(a_s[s*4+h] + adnB + ea.x*m2a + ea.y*m2b));
      denomB += pe;
      __half2 pe2 = __float2half2_rn(pe);
      __half2* y = reinterpret_cast<__half2*>(&u);
      accB0=__hfma2(y[0],pe2,accB0); accB1=__hfma2(y[1],pe2,accB1);
      accB2=__hfma2(y[2],pe2,accB2); accB3=__hfma2(y[3],pe2,accB3);
    }
  }
  // finalize A
  {
    float sc = 0.25f/denomA;
    float a[8];
    a[0]=__low2float(accA0); a[1]=__high2float(accA0);
    a[2]=__low2float(accA1); a[3]=__high2float(accA1);
    a[4]=__low2float(accA2); a[5]=__high2float(accA2);
    a[6]=__low2float(accA3); a[7]=__high2float(accA3);
    #pragma unroll
    for (int j=0;j<8;j++){
      a[j] *= sc;
      a[j] += __shfl_xor(a[j], 16);
      a[j] += __shfl_xor(a[j], 32);
    }
    if (lane < 16){
      int c = lane*8;
      float4 bb0 = *reinterpret_cast<const float4*>(&bias[c]);
      float4 bb1 = *reinterpret_cast<const float4*>(&bias[c+4]);
      __half2 hv[4];
      hv[0] = __floats2half2_rn(a[0]+bb0.x, a[1]+bb0.y);
      hv[1] = __floats2half2_rn(a[2]+bb0.z, a[3]+bb0.w);
      hv[2] = __floats2half2_rn(a[4]+bb1.x, a[5]+bb1.y);
      hv[3] = __floats2half2_rn(a[6]+bb1.z, a[7]+bb1.w);
      *reinterpret_cast<uint4*>(out + (size_t)nA*128 + c) = *reinterpret_cast<uint4*>(hv);
    }
  }
  // finalize B
  {
    float sc = 0.25f/denomB;
    float a[8];
    a[0]=__low2float(accB0); a[1]=__high2float(accB0);
    a[2]=__low2float(accB1); a[3]=__high2float(accB1);
    a[4]=__low2float(accB2); a[5]=__high2float(accB2);
    a[6]=__low2float(accB3); a[7]=__high2float(accB3);
    #pragma unroll
    for (int j=0;j<8;j++){
      a[j] *= sc;
      a[j] += __shfl_xor(a[j], 16);
      a[j] += __shfl_xor(a[j], 32);
    }
    if (lane < 16){
      int c = lane*8;
      float4 bb0 = *reinterpret_cast<const float4*>(&bias[c]);
      float4 bb1 = *reinterpret_cast<const float4*>(&bias[c+4]);
      __half2 hv[4];
      hv[0] = __floats2half2_rn(a[0]+bb0.x, a[1]+bb0.y);
      hv[1] = __floats2half2_rn(a[2]+bb0.z, a[3]+bb0.w);
      hv[2] = __floats2half2_rn(a[4]+bb1.x, a[5]+bb1.y);
      hv[3] = __floats2half2_rn(a[6]+bb1.z, a[7]+bb1.w);
      *reinterpret_cast<uint4*>(out + (size_t)nB*128 + c) = *reinterpret_cast<uint4*>(hv);
    }
  }
}

// ---------------- graph norm (per-block partials, no atomics; f16 input) ----------------
__global__ __launch_bounds__(256) void k_colstat(const __half* __restrict__ X, float* __restrict__ part){
  int d = threadIdx.x & 127;
  int rg = threadIdx.x >> 7;
  float s1=0.f, s2=0.f;
  for (int n = blockIdx.x*2 + rg; n < NNODES; n += 512){
    float v = __half2float(X[(size_t)n*128 + d]);
    s1 += v; s2 = fmaf(v, v, s2);
  }
  __shared__ float sh[512];
  sh[threadIdx.x] = s1; sh[256+threadIdx.x] = s2;
  __syncthreads();
  if (threadIdx.x < 128){
    s1 = sh[threadIdx.x] + sh[threadIdx.x+128];
    s2 = sh[256+threadIdx.x] + sh[256+threadIdx.x+128];
    part[blockIdx.x*256 + d]       = s1;
    part[blockIdx.x*256 + 128 + d] = s2;
  }
}
__global__ __launch_bounds__(128) void k_finstat(const float* __restrict__ part,
                         const float* __restrict__ w, const float* __restrict__ b, const float* __restrict__ ms,
                         float* __restrict__ scaleA, float* __restrict__ shiftB){
  int d = threadIdx.x;
  float s1=0.f, s2=0.f;
  for (int bq=0; bq<256; bq++){ s1 += part[bq*256 + d]; s2 += part[bq*256 + 128 + d]; }
  float mean = s1 * (1.f/NNODES);
  float ex2  = s2 * (1.f/NNODES);
  float m = ms[d];
  float var = ex2 - m*mean*mean*(2.f - m);
  float sc = w[d] * rsqrtf(var + EPSV);
  scaleA[d] = sc;
  shiftB[d] = b[d] - sc*m*mean;
}
// norm + residual(bf16) + ELU; o is f16; write bf16 X (or f32 final output)
__global__ __launch_bounds__(256) void k_normelu(const __half* __restrict__ o, unsigned short* __restrict__ xb,
                         const float* __restrict__ scaleA, const float* __restrict__ shiftB,
                         float* __restrict__ fout){
  int i = blockIdx.x*256 + threadIdx.x;
  int stride = gridDim.x*256;
  for (; i < NNODES*32; i += stride){
    int d4 = i & 31;
    uint2 ou = ((const uint2*)o)[i];
    __half2* oh = reinterpret_cast<__half2*>(&ou);
    float o0 = __low2float(oh[0]), o1 = __high2float(oh[0]);
    float o2 = __low2float(oh[1]), o3 = __high2float(oh[1]);
    uint2 xu = ((const uint2*)xb)[i];
    float4 sc = ((const float4*)scaleA)[d4];
    float4 sh = ((const float4*)shiftB)[d4];
    float xi0 = __uint_as_float(xu.x<<16), xi1 = __uint_as_float(xu.x & 0xffff0000u);
    float xi2 = __uint_as_float(xu.y<<16), xi3 = __uint_as_float(xu.y & 0xffff0000u);
    float4 r; float y;
    y = fmaf(sc.x, o0, sh.x) + xi0; r.x = y > 0.f ? y : expm1f(y);
    y = fmaf(sc.y, o1, sh.y) + xi1; r.y = y > 0.f ? y : expm1f(y);
    y = fmaf(sc.z, o2, sh.z) + xi2; r.z = y > 0.f ? y : expm1f(y);
    y = fmaf(sc.w, o3, sh.w) + xi3; r.w = y > 0.f ? y : expm1f(y);
    if (fout){
      ((float4*)fout)[i] = r;
    } else {
      uint2 u; u.x = pk2(r.x, r.y); u.y = pk2(r.z, r.w);
      ((uint2*)xb)[i] = u;
    }
  }
}

// ---------------- host launch ----------------
extern "C" void kernel_launch(void* const* d_in, const int* in_sizes, int n_in,
                              void* d_out, int out_size, void* d_ws, size_t ws_size,
                              hipStream_t stream)
{
  const float* extra    = (const float*)d_in[0];
  const int*   ei       = (const int*)  d_in[1];
  const float* eattr    = (const float*)d_in[2];
  const int*   clus     = (const int*)  d_in[3];
  const float* user     = (const float*)d_in[4];
  const float* item     = (const float*)d_in[5];
  const float* W1       = (const float*)d_in[6];
  const float* b1       = (const float*)d_in[7];
  const float* W2       = (const float*)d_in[8];
  const float* b2       = (const float*)d_in[9];
  const float* gcnW     = (const float*)d_in[10];
  const float* gcnb     = (const float*)d_in[11];
  const float* g_lin    = (const float*)d_in[12];
  const float* g_lin_e  = (const float*)d_in[13];
  const float* g_att_s  = (const float*)d_in[14];
  const float* g_att_d  = (const float*)d_in[15];
  const float* g_att_e  = (const float*)d_in[16];
  const float* g_bias   = (const float*)d_in[17];
  const float* gat_lin  = (const float*)d_in[18];
  const float* gat_lin_e= (const float*)d_in[19];
  const float* gat_att_s= (const float*)d_in[20];
  const float* gat_att_d= (const float*)d_in[21];
  const float* gat_att_e= (const float*)d_in[22];
  const float* gat_bias = (const float*)d_in[23];
  const float* nw_      = (const float*)d_in[24];
  const float* nb_      = (const float*)d_in[25];
  const float* nms_     = (const float*)d_in[26];

  char* ws = (char*)d_ws;
  size_t off = 0;
  auto alloc = [&](size_t bytes)->char*{
    char* p = ws + off;
    off += (bytes + 255) & ~size_t(255);
    return p;
  };

  float* bufX = (float*)alloc((size_t)NNODES*128*4);
  float* bufY = (float*)alloc((size_t)NNODES*128*4);
  float* bufZ = (float*)alloc((size_t)NNODES*128*4);
  // shared "big" region (disjoint lifetimes):
  //   [0,20.5MB)    Xbf   (live from k_xcomb to end)
  //   [22,104MB)    XHf   (live during GAT layers only)
  //   [22,28.3MB)   pcb/pa0b/pa1b (pairhist phase, before MLP)
  //   [22,37.4MB)   Hbf   (MLP phase only)
  //   [40,53.1MB)   ppart (pool phase, before layers)
  char* big = alloc((size_t)112*1024*1024);
  unsigned short* Xbf   = (unsigned short*)big;
  unsigned short* XHf   = (unsigned short*)(big + (size_t)22*1024*1024);
  unsigned short* Hbf   = (unsigned short*)(big + (size_t)22*1024*1024);
  float* pcb  = (float*)(big + (size_t)22*1024*1024);
  float* pa0b = pcb  + 4096*128;
  float* pa1b = pa0b + 4096*128;
  float* ppart = (float*)(big + (size_t)40*1024*1024);
  int* offs   = (int*)alloc((NNODES+1)*4);
  int* ioffs  = (int*)alloc((NNODES+1)*4);
  int* bsum   = (int*)alloc(1024*4);
  int* bsum2  = (int*)alloc(1024*4);
  int2* csr   = (int2*)alloc((size_t)NEDGES*8);
  int* csr2   = (int*)alloc((size_t)NEDGES*4);
  float* a_s  = (float*)alloc((size_t)NNODES*4*4);
  float* a_d  = (float*)alloc((size_t)NNODES*4*4);
  // zeroed-per-call region (single memset)
  char* zero0 = ws + off;
  int*   cnt      = (int*)  alloc((size_t)NNODES*4);
  int*   intra    = (int*)  alloc((size_t)NNODES*4);
  int*   cursor   = (int*)  alloc((size_t)NNODES*4);
  int*   cursor2  = (int*)  alloc((size_t)NNODES*4);
  int*   csize    = (int*)  alloc(256*4);
  float* la       = (float*)alloc((size_t)NNODES*2*4);
  size_t zbytes = (size_t)((ws + off) - zero0);
  // small buffers
  float* pooled= (float*)alloc(8192*4);
  float* M2g   = (float*)alloc(8*4);
  float* M2    = (float*)alloc(24*4);
  float* pair_cnt = (float*)alloc(4096*4);
  float* avg_attr = (float*)alloc(8192*4);
  float* loop_c   = (float*)alloc(128*4);
  float* xh_c     = (float*)alloc(64*512*4);
  float* a_s_c    = (float*)alloc(256*4);
  float* a_d_c    = (float*)alloc(256*4);
  float* cl_out   = (float*)alloc(64*128*4);
  float* colpart  = (float*)alloc(256*256*4);
  float* scaleA   = (float*)alloc(128*4);
  float* shiftB   = (float*)alloc(128*4);
  unsigned short* W1t  = (unsigned short*)alloc((size_t)896*256*2);
  unsigned short* W2t  = (unsigned short*)alloc((size_t)256*128*2);
  unsigned short* gcnWt= (unsigned short*)alloc((size_t)128*128*2);
  unsigned short* glt  = (unsigned short*)alloc((size_t)3*128*512*2);
  if (off > ws_size) return;

  hipMemsetAsync(zero0, 0, zbytes, stream);

  const int NB = (NNODES+255)/256;
  // phase 0: pair hist + cnt/intra, reduce; dual scans (cnt -> offs, intra -> ioffs); fused fill
  k_pairhist<<<128, 1024, 0, stream>>>(ei, eattr, clus, cnt, intra, pcb, pa0b, pa1b);
  k_pairreduce<<<64, 64, 0, stream>>>(pcb, pa0b, pa1b, pair_cnt, avg_attr);
  k_scan_block<<<NB, 256, 0, stream>>>(cnt, offs, bsum, NNODES, clus, csize);
  k_scan_block<<<NB, 256, 0, stream>>>(intra, ioffs, bsum2, NNODES, nullptr, nullptr);
  k_scan_bsum<<<1, 512, 0, stream>>>(bsum, NB);
  k_scan_bsum<<<1, 512, 0, stream>>>(bsum2, NB);
  k_scan_add<<<NB, 256, 0, stream>>>(offs, bsum, NNODES, NEDGES);
  k_scan_add<<<NB, 256, 0, stream>>>(ioffs, bsum2, NNODES, 0);
  k_fill_csr<<<(NEDGES+255)/256, 256, 0, stream>>>(ei, eattr, clus, offs, ioffs,
                                                   cursor, cursor2, csr, csr2, la);

  // small precomputes + weight conversions
  k_m2<<<1, 64, 0, stream>>>(g_lin_e, g_att_e, gat_lin_e, gat_att_e, M2g, M2);
  k_wtall<<<(475136+255)/256, 256, 0, stream>>>(W1, W2, gcnW, gat_lin, W1t, W2t, gcnWt, glt);

  // enrichment MLP (bf16 MFMA, f32-A fused conversion); Hbf reuses dead pairhist region
  {
    dim3 g1((N_ITEMS+127)/128, 2);
    k_mgemm<1,1,1,1,1,0><<<g1, 256, 0, stream>>>((const void*)item, extra, W1t, b1, (void*)Hbf,
                                                 N_ITEMS, 256, 896, 128, nullptr, nullptr, nullptr, nullptr);
    dim3 g2((N_ITEMS+127)/128, 1);
    k_mgemm<0,0,0,0,1,0><<<g2, 256, 0, stream>>>((const void*)Hbf, nullptr, W2t, b2,
                                                 (void*)(bufX + (size_t)N_USERS*128),
                                                 N_ITEMS, 128, 256, 0, nullptr, nullptr, nullptr, nullptr);
  }
  hipMemcpyAsync(bufX, user, (size_t)N_USERS*128*4, hipMemcpyDeviceToDevice, stream);

  // cluster GCN: XW (f16) = X @ gcnW; aggregate over intra-CSR only
  {
    dim3 g3((NNODES+127)/128, 1);
    k_mgemm<1,0,2,0,0,0><<<g3, 256, 0, stream>>>((const void*)bufX, nullptr, gcnWt, nullptr, (void*)bufY,
                                                 NNODES, 128, 128, 0, nullptr, nullptr, nullptr, nullptr);
  }
  k_gcn<<<5000, 256, 0, stream>>>((const unsigned short*)bufY, ioffs, csr2, intra, gcnb, bufZ);

  // pooling (LDS partials) + cluster GAT
  k_pool1<<<400, 256, 0, stream>>>(bufZ, clus, ppart);
  k_pool2<<<32, 256, 0, stream>>>(ppart, csize, pooled);
  {
    dim3 g4(1, 4);
    k_sgemm<0,0><<<g4, 256, 0, stream>>>(pooled, nullptr, g_lin, nullptr, xh_c, 64, 512, 128, 0);
  }
  k_loop_c<<<1, 64, 0, stream>>>(pair_cnt, avg_attr, loop_c);
  k_asc<<<1, 256, 0, stream>>>(xh_c, g_att_s, g_att_d, a_s_c, a_d_c);
  k_clout<<<64, 128, 0, stream>>>(a_s_c, a_d_c, loop_c, M2g, pair_cnt, avg_attr, xh_c, g_bias, cl_out);
  k_xcomb<<<1280, 256, 0, stream>>>(bufZ, cl_out, clus, Xbf);

  // 3 GAT layers (X in Xbf bf16; xh in f16; a_s/a_d fused in GEMM epilogue; dual-node k_gat)
  for (int l = 0; l < 3; ++l){
    dim3 gx((NNODES+127)/128, 4);
    k_mgemm<0,0,2,0,0,1><<<gx, 256, 0, stream>>>((const void*)Xbf, nullptr, glt + (size_t)l*65536, nullptr,
                                                 (void*)XHf, NNODES, 512, 128, 0,
                                                 gat_att_s + l*512, gat_att_d + l*512, a_s, a_d);
    k_gat<<<NHALF/4, 256, 0, stream>>>(XHf, a_s, a_d, eattr, offs, csr, la,
                                       M2 + l*8, gat_bias + l*128, (__half*)bufY);
    k_colstat<<<256, 256, 0, stream>>>((const __half*)bufY, colpart);
    k_finstat<<<1, 128, 0, stream>>>(colpart, nw_ + l*128, nb_ + l*128, nms_ + l*128, scaleA, shiftB);
    k_normelu<<<1280, 256, 0, stream>>>((const __half*)bufY, Xbf, scaleA, shiftB, (l==2) ? (float*)d_out : nullptr);
  }
}

// Round 11
// 1445.873 us; speedup vs baseline: 1.0127x; 1.0127x over previous
//
#include <hip/hip_runtime.h>
#include <hip/hip_fp16.h>
#include <math.h>

#define N_USERS 50000
#define N_ITEMS 30000
#define NNODES  80000
#define NEDGES  640000
#define NCLUS   64
#define NEG     0.2f
#define EPSV    1e-5f

typedef __attribute__((ext_vector_type(8))) short bf16x8;
typedef __attribute__((ext_vector_type(4))) float f32x4;

__device__ __forceinline__ float lrelu(float x){ return x > 0.f ? x : NEG*x; }

__device__ __forceinline__ unsigned short f2bf(float f){
  unsigned u = __float_as_uint(f);
  u += 0x7fffu + ((u>>16)&1u);
  return (unsigned short)(u>>16);
}
__device__ __forceinline__ unsigned short f2h(float f){
  __half h = __float2half(f);
  return *reinterpret_cast<unsigned short*>(&h);
}
__device__ __forceinline__ unsigned pk2(float lo, float hi){
  return (unsigned)f2bf(lo) | ((unsigned)f2bf(hi) << 16);
}
__device__ __forceinline__ float4 f4add(float4 a, float4 b){
  return make_float4(a.x+b.x, a.y+b.y, a.z+b.z, a.w+b.w);
}

// ---------------- phase 0: pair histogram (LDS-aggregated, 1024-thread blocks) ----------------
__global__ __launch_bounds__(1024) void k_pairhist(
    const int* __restrict__ ei, const float* __restrict__ eattr, const int* __restrict__ clus,
    int* __restrict__ cnt, int* __restrict__ intra,
    float* __restrict__ pcb, float* __restrict__ pa0b, float* __restrict__ pa1b)
{
  __shared__ float pc[4096];
  __shared__ float pa0[4096];
  __shared__ float pa1[4096];
  for (int i=threadIdx.x; i<4096; i+=1024){ pc[i]=0.f; pa0[i]=0.f; pa1[i]=0.f; }
  __syncthreads();
  for (int e = blockIdx.x*1024 + threadIdx.x; e < NEDGES; e += 128*1024){
    int s = ei[e], d = ei[NEDGES+e];
    int cu = clus[s], cv = clus[d];
    atomicAdd(&cnt[d], 1);
    if (cu == cv) { atomicAdd(&intra[d], 1); }
    else {
      float2 a = *reinterpret_cast<const float2*>(&eattr[2*e]);
      int k = cu*NCLUS + cv;
      atomicAdd(&pc[k], 1.f);
      atomicAdd(&pa0[k], a.x);
      atomicAdd(&pa1[k], a.y);
    }
  }
  __syncthreads();
  int b = blockIdx.x;
  for (int i=threadIdx.x; i<4096; i+=1024){
    pcb [i*128 + b] = pc[i];
    pa0b[i*128 + b] = pa0[i];
    pa1b[i*128 + b] = pa1[i];
  }
}

__global__ __launch_bounds__(64) void k_pairreduce(
    const float* __restrict__ pcb, const float* __restrict__ pa0b, const float* __restrict__ pa1b,
    float* __restrict__ pair_cnt, float* __restrict__ avg_attr)
{
  int i = blockIdx.x*64 + threadIdx.x;  // 4096 total over grid 64
  float c=0.f, s0=0.f, s1=0.f;
  const float4* P0 = (const float4*)(pcb  + (size_t)i*128);
  const float4* P1 = (const float4*)(pa0b + (size_t)i*128);
  const float4* P2 = (const float4*)(pa1b + (size_t)i*128);
  for (int b=0;b<32;b++){
    float4 v0=P0[b], v1=P1[b], v2=P2[b];
    c  += v0.x+v0.y+v0.z+v0.w;
    s0 += v1.x+v1.y+v1.z+v1.w;
    s1 += v2.x+v2.y+v2.z+v2.w;
  }
  pair_cnt[i] = c;
  float inv = 1.f/fmaxf(c, 1.f);
  avg_attr[2*i]   = s0*inv;
  avg_attr[2*i+1] = s1*inv;
}

// scan block (+ optional node histogram)
__global__ __launch_bounds__(256) void k_scan_block(const int* __restrict__ in, int* __restrict__ out,
                                                    int* __restrict__ bsum, int n,
                                                    const int* __restrict__ clus, int* __restrict__ csize){
  __shared__ int buf[256];
  int i = blockIdx.x*256 + threadIdx.x;
  int v = (i < n) ? in[i] : 0;
  if (csize && i < n) atomicAdd(&csize[clus[i]], 1);
  buf[threadIdx.x] = v; __syncthreads();
  for (int off=1; off<256; off<<=1){
    int t = (threadIdx.x>=off) ? buf[threadIdx.x-off] : 0;
    __syncthreads();
    buf[threadIdx.x] += t;
    __syncthreads();
  }
  if (i < n) out[i] = buf[threadIdx.x] - v;
  if (threadIdx.x == 255) bsum[blockIdx.x] = buf[255];
}

__global__ __launch_bounds__(512) void k_scan_bsum(int* __restrict__ bsum, int nb){
  __shared__ int buf[512];
  int v = (threadIdx.x < nb) ? bsum[threadIdx.x] : 0;
  buf[threadIdx.x] = v; __syncthreads();
  for (int off=1; off<512; off<<=1){
    int t = (threadIdx.x>=off) ? buf[threadIdx.x-off] : 0;
    __syncthreads();
    buf[threadIdx.x] += t;
    __syncthreads();
  }
  if (threadIdx.x < nb) bsum[threadIdx.x] = buf[threadIdx.x] - v;
}

__global__ __launch_bounds__(256) void k_scan_add(int* __restrict__ out, const int* __restrict__ bsum,
                                                  int n, int total){
  int i = blockIdx.x*256 + threadIdx.x;
  if (i < n) out[i] += bsum[i>>8];
  if (i == 0) out[n] = total;
}

// fill main CSR + intra CSR + la (loop-attr sums), all in one pass
__global__ __launch_bounds__(256) void k_fill_csr(const int* __restrict__ ei, const float* __restrict__ eattr,
                                                  const int* __restrict__ clus,
                                                  const int* __restrict__ offs, const int* __restrict__ ioffs,
                                                  int* __restrict__ cursor, int* __restrict__ cursor2,
                                                  int2* __restrict__ csr, int* __restrict__ csr2,
                                                  float* __restrict__ la){
  int e = blockIdx.x*256 + threadIdx.x;
  if (e >= NEDGES) return;
  int s = ei[e], d = ei[NEDGES+e];
  int pos = offs[d] + atomicAdd(&cursor[d], 1);
  csr[pos] = make_int2(s, e);
  float2 a = *reinterpret_cast<const float2*>(&eattr[2*e]);
  atomicAdd(&la[2*d],   a.x);
  atomicAdd(&la[2*d+1], a.y);
  if (clus[s] == clus[d]){
    int p2 = ioffs[d] + atomicAdd(&cursor2[d], 1);
    csr2[p2] = s;
  }
}

// ---------------- all weight transposes+converts in one kernel ----------------
__global__ __launch_bounds__(256) void k_wtall(const float* __restrict__ W1, const float* __restrict__ W2,
                       const float* __restrict__ gcnW, const float* __restrict__ gat_lin,
                       unsigned short* __restrict__ W1t, unsigned short* __restrict__ W2t,
                       unsigned short* __restrict__ gcnWt, unsigned short* __restrict__ glt){
  int i = blockIdx.x*256 + threadIdx.x;
  if (i < 229376){            // W1: K=896, N=256
    int n = i/896, k = i - n*896;
    W1t[i] = f2bf(W1[(size_t)k*256 + n]);
  } else if (i < 262144){     // W2: K=256, N=128
    int j = i - 229376; int n = j/256, k = j - n*256;
    W2t[j] = f2bf(W2[(size_t)k*128 + n]);
  } else if (i < 278528){     // gcnW: 128x128
    int j = i - 262144; int n = j/128, k = j - n*128;
    gcnWt[j] = f2bf(gcnW[(size_t)k*128 + n]);
  } else if (i < 475136){     // gat_lin: 3 x (K=128, N=512)
    int j = i - 278528; int l = j >> 16; int r = j & 65535; int n = r/128, k = r - n*128;
    glt[j] = f2bf(gat_lin[(size_t)l*65536 + (size_t)k*512 + n]);
  }
}

// ---------------- bf16 MFMA GEMM: C = act(A @ Bt^T + bias) ----------------
// AF32: A is f32 (converted during staging); CONCAT: A|A2 split at K1.
// OUT: 0=f32, 1=bf16, 2=f16 (16-bit outs use LDS repack + coalesced uint4 stores)
// ASD: also emit a_s/a_d per-row dots with attS/attD (blockIdx.y = head).
template<int AF32, int CONCAT, int OUT, int RELU, int BIAS, int ASD>
__global__ __launch_bounds__(256)
void k_mgemm(const void* __restrict__ Av, const float* __restrict__ A2,
             const unsigned short* __restrict__ Bt, const float* __restrict__ bias,
             void* __restrict__ Cv, int M, int N, int K, int K1,
             const float* __restrict__ attS, const float* __restrict__ attD,
             float* __restrict__ oas, float* __restrict__ oad)
{
  __shared__ unsigned short smem[128*128];   // 32KB: A-stage [0,8192), B-stage [8192,16384); C-repack uses all
  unsigned short* As = smem;
  unsigned short* Bs = smem + 128*64;
  __shared__ float sAs[2][128], sAd[2][128];
  const int tid = threadIdx.x;
  const int lane = tid & 63, w = tid >> 6;
  const int row0 = blockIdx.x*128, col0 = blockIdx.y*128;
  const int wm = w >> 1, wn = w & 1;
  const int l15 = lane & 15, l4 = lane >> 4;
  f32x4 acc[4][4];
  #pragma unroll
  for (int i=0;i<4;i++)
    #pragma unroll
    for (int n=0;n<4;n++) acc[i][n] = (f32x4){0.f,0.f,0.f,0.f};

  const int rr0 = w*32 + (lane>>3);
  const int cA = lane & 7;

  for (int kt = 0; kt < K; kt += 64){
    uint4 ra[4], rb[4];
    #pragma unroll
    for (int i=0;i<4;i++){
      int rr = rr0 + i*8;
      int ga = row0 + rr; ga = (ga < M) ? ga : (M-1);
      int gb = col0 + rr; gb = (gb < N) ? gb : (N-1);
      int gk = kt + cA*8;
      if (AF32){
        const float* Af = (const float*)Av;
        const float* src;
        if (CONCAT && gk >= K1) src = A2 + (size_t)ga*(K-K1) + (gk - K1);
        else                    src = Af + (size_t)ga*(CONCAT ? K1 : K) + gk;
        float4 f0 = ((const float4*)src)[0];
        float4 f1 = ((const float4*)src)[1];
        ra[i] = make_uint4(pk2(f0.x,f0.y), pk2(f0.z,f0.w), pk2(f1.x,f1.y), pk2(f1.z,f1.w));
      } else {
        ra[i] = *reinterpret_cast<const uint4*>((const unsigned short*)Av + (size_t)ga*K + gk);
      }
      rb[i] = *reinterpret_cast<const uint4*>(Bt + (size_t)gb*K + gk);
    }
    __syncthreads();
    #pragma unroll
    for (int i=0;i<4;i++){
      int rr = rr0 + i*8;
      int ch = cA ^ (rr & 7);
      *reinterpret_cast<uint4*>(&As[rr*64 + ch*8]) = ra[i];
      *reinterpret_cast<uint4*>(&Bs[rr*64 + ch*8]) = rb[i];
    }
    __syncthreads();
    #pragma unroll
    for (int k0=0;k0<2;k0++){
      bf16x8 af[4], bff[4];
      #pragma unroll
      for (int i=0;i<4;i++){
        int row = wm*64 + i*16 + l15;
        int ch = (k0*4 + l4) ^ (row & 7);
        af[i] = *reinterpret_cast<const bf16x8*>(&As[row*64 + ch*8]);
      }
      #pragma unroll
      for (int n=0;n<4;n++){
        int row = wn*64 + n*16 + l15;
        int ch = (k0*4 + l4) ^ (row & 7);
        bff[n] = *reinterpret_cast<const bf16x8*>(&Bs[row*64 + ch*8]);
      }
      #pragma unroll
      for (int i=0;i<4;i++)
        #pragma unroll
        for (int n=0;n<4;n++)
          acc[i][n] = __builtin_amdgcn_mfma_f32_16x16x32_bf16(af[i], bff[n], acc[i][n], 0, 0, 0);
    }
  }
  if (ASD){
    const float* aSb = attS + (size_t)blockIdx.y*128;
    const float* aDb = attD + (size_t)blockIdx.y*128;
    float aS[4], aD[4];
    #pragma unroll
    for (int n=0;n<4;n++){
      int c = wn*64 + n*16 + l15;
      aS[n] = aSb[c]; aD[n] = aDb[c];
    }
    float ps[4][4], pd[4][4];
    #pragma unroll
    for (int i=0;i<4;i++)
      #pragma unroll
      for (int r=0;r<4;r++){
        float s=0.f, d=0.f;
        #pragma unroll
        for (int n=0;n<4;n++){
          s = fmaf(acc[i][n][r], aS[n], s);
          d = fmaf(acc[i][n][r], aD[n], d);
        }
        ps[i][r]=s; pd[i][r]=d;
      }
    #pragma unroll
    for (int m=1;m<16;m<<=1){
      #pragma unroll
      for (int i=0;i<4;i++)
        #pragma unroll
        for (int r=0;r<4;r++){
          ps[i][r] += __shfl_xor(ps[i][r], m);
          pd[i][r] += __shfl_xor(pd[i][r], m);
        }
    }
    if (l15 == 0){
      #pragma unroll
      for (int i=0;i<4;i++)
        #pragma unroll
        for (int r=0;r<4;r++){
          int rl = wm*64 + i*16 + l4*4 + r;
          sAs[wn][rl] = ps[i][r];
          sAd[wn][rl] = pd[i][r];
        }
    }
    __syncthreads();
    if (tid < 128){
      int row = row0 + tid;
      if (row < M){
        int head = blockIdx.y;
        oas[(size_t)row*4 + head] = sAs[0][tid] + sAs[1][tid];
        oad[(size_t)row*4 + head] = sAd[0][tid] + sAd[1][tid];
      }
    }
  }
  // C store
  if (OUT == 1 || OUT == 2){
    __syncthreads();
    #pragma unroll
    for (int i=0;i<4;i++){
      #pragma unroll
      for (int n=0;n<4;n++){
        int cl = wn*64 + n*16 + l15;
        float bv = BIAS ? bias[col0+cl] : 0.f;
        #pragma unroll
        for (int r=0;r<4;r++){
          int rl = wm*64 + i*16 + l4*4 + r;
          float y = acc[i][n][r] + bv;
          if (RELU) y = fmaxf(y, 0.f);
          smem[rl*128 + cl] = (OUT == 1) ? f2bf(y) : f2h(y);
        }
      }
    }
    __syncthreads();
    #pragma unroll
    for (int t = tid; t < 128*16; t += 256){
      int row = t >> 4, chunk = t & 15;
      int grow = row0 + row;
      if (grow < M)
        *reinterpret_cast<uint4*>((unsigned short*)Cv + (size_t)grow*N + col0 + chunk*8)
          = *reinterpret_cast<const uint4*>(&smem[row*128 + chunk*8]);
    }
  } else {
    #pragma unroll
    for (int i=0;i<4;i++){
      int rowb = row0 + wm*64 + i*16 + l4*4;
      #pragma unroll
      for (int n=0;n<4;n++){
        int col = col0 + wn*64 + n*16 + l15;
        float bv = BIAS ? bias[col] : 0.f;
        #pragma unroll
        for (int r=0;r<4;r++){
          int row = rowb + r;
          if (row < M){
            float y = acc[i][n][r] + bv;
            if (RELU) y = fmaxf(y, 0.f);
            ((float*)Cv)[(size_t)row*N + col] = y;
          }
        }
      }
    }
  }
}

// ---------------- f32 SGEMM (tiny pooled GEMM only) ----------------
template<int CONCAT, int ACT>
__global__ __launch_bounds__(256)
void k_sgemm(const float* __restrict__ A, const float* __restrict__ A2,
             const float* __restrict__ B, const float* __restrict__ bias,
             float* __restrict__ C, int M, int N, int K, int K1)
{
  __shared__ float As[8][128];
  __shared__ float Bs[8][128];
  int row0 = blockIdx.x*128, col0 = blockIdx.y*128;
  int tid = threadIdx.x;
  int tx = tid & 15, ty = tid >> 4;
  float acc[8][8];
  #pragma unroll
  for (int i=0;i<8;i++)
    #pragma unroll
    for (int j=0;j<8;j++) acc[i][j]=0.f;

  int arow = tid >> 1, acol = (tid & 1)*4;
  int brow = tid >> 5, bcol = (tid & 31)*4;
  int K2 = K - K1;

  for (int k0=0; k0<K; k0+=8){
    float4 av = make_float4(0.f,0.f,0.f,0.f);
    int gr = row0 + arow, gk = k0 + acol;
    if (gr < M){
      if (CONCAT){
        if (gk < K1) av = *reinterpret_cast<const float4*>(&A [(size_t)gr*K1 + gk]);
        else         av = *reinterpret_cast<const float4*>(&A2[(size_t)gr*K2 + (gk-K1)]);
      } else {
        av = *reinterpret_cast<const float4*>(&A[(size_t)gr*K + gk]);
      }
    }
    As[acol+0][arow]=av.x; As[acol+1][arow]=av.y; As[acol+2][arow]=av.z; As[acol+3][arow]=av.w;
    float4 bv = *reinterpret_cast<const float4*>(&B[(size_t)(k0+brow)*N + col0 + bcol]);
    *reinterpret_cast<float4*>(&Bs[brow][bcol]) = bv;
    __syncthreads();
    #pragma unroll
    for (int kk=0; kk<8; ++kk){
      float a[8], b[8];
      *(float4*)&a[0] = *(float4*)&As[kk][ty*8];
      *(float4*)&a[4] = *(float4*)&As[kk][ty*8+4];
      *(float4*)&b[0] = *(float4*)&Bs[kk][tx*8];
      *(float4*)&b[4] = *(float4*)&Bs[kk][tx*8+4];
      #pragma unroll
      for (int i=0;i<8;i++)
        #pragma unroll
        for (int j=0;j<8;j++) acc[i][j] = fmaf(a[i], b[j], acc[i][j]);
    }
    __syncthreads();
  }
  #pragma unroll
  for (int i=0;i<8;i++){
    int r = row0 + ty*8 + i;
    if (r >= M) continue;
    #pragma unroll
    for (int j4=0;j4<2;j4++){
      int c = col0 + tx*8 + j4*4;
      float4 v = make_float4(acc[i][j4*4], acc[i][j4*4+1], acc[i][j4*4+2], acc[i][j4*4+3]);
      if (bias){
        float4 bb = *reinterpret_cast<const float4*>(&bias[c]);
        v = f4add(v, bb);
      }
      if (ACT == 1){
        v.x=fmaxf(v.x,0.f); v.y=fmaxf(v.y,0.f); v.z=fmaxf(v.z,0.f); v.w=fmaxf(v.w,0.f);
      }
      *reinterpret_cast<float4*>(&C[(size_t)r*N + c]) = v;
    }
  }
}

// ---------------- GCN aggregation (intra-CSR: only intra-cluster edges) ----------------
__global__ __launch_bounds__(256) void k_gcn(const unsigned short* __restrict__ XWh, const int* __restrict__ ioffs,
                      const int* __restrict__ csr2, const int* __restrict__ intra,
                      const float* __restrict__ gcn_b, float* __restrict__ Xc)
{
  int wid  = (blockIdx.x*blockDim.x + threadIdx.x) >> 6;
  int lane = threadIdx.x & 63;
  int nw   = (gridDim.x*blockDim.x) >> 6;
  for (int n = wid; n < NNODES; n += nw){
    int cntn = intra[n];
    float deg = 1.f + (float)cntn;
    float dinv_n = rsqrtf(deg);
    __half2 hx = *reinterpret_cast<const __half2*>(XWh + (size_t)n*128 + lane*2);
    float2 acc;
    acc.x = __low2float(hx)/deg; acc.y = __high2float(hx)/deg;
    int io0 = ioffs[n];
    for (int j=0; j<cntn; ++j){
      int s = csr2[io0+j];
      float w = dinv_n * rsqrtf(1.f + (float)intra[s]);
      __half2 hs = *reinterpret_cast<const __half2*>(XWh + (size_t)s*128 + lane*2);
      acc.x = fmaf(w, __low2float(hs), acc.x);
      acc.y = fmaf(w, __high2float(hs), acc.y);
    }
    float2 bb = *reinterpret_cast<const float2*>(&gcn_b[lane*2]);
    acc.x += bb.x; acc.y += bb.y;
    *reinterpret_cast<float2*>(&Xc[(size_t)n*128 + lane*2]) = acc;
  }
}

// ---------------- cluster pooling: LDS partials + reduce ----------------
__global__ __launch_bounds__(256) void k_pool1(const float* __restrict__ Xc, const int* __restrict__ clus,
                                               float* __restrict__ part){
  __shared__ float lp[8192];
  for (int i=threadIdx.x; i<8192; i+=256) lp[i]=0.f;
  __syncthreads();
  int d = threadIdx.x & 127, rg = threadIdx.x >> 7;
  int n0 = blockIdx.x*200;
  for (int n = n0+rg; n < n0+200; n += 2){
    int c = clus[n];
    atomicAdd(&lp[c*128 + d], Xc[(size_t)n*128 + d]);
  }
  __syncthreads();
  for (int i=threadIdx.x; i<8192; i+=256) part[(size_t)blockIdx.x*8192 + i] = lp[i];
}
__global__ __launch_bounds__(256) void k_pool2(const float* __restrict__ part, const int* __restrict__ csize,
                                               float* __restrict__ pooled){
  int i = blockIdx.x*256 + threadIdx.x; // 8192
  float s = 0.f;
  for (int b=0;b<400;b++) s += part[(size_t)b*8192 + i];
  pooled[i] = s / fmaxf((float)csize[i>>7], 1.f);
}

// ---------------- small precomputes ----------------
__global__ __launch_bounds__(64) void k_m2(const float* __restrict__ g_lin_e, const float* __restrict__ g_att_e,
                    const float* __restrict__ gat_lin_e, const float* __restrict__ gat_att_e,
                    float* __restrict__ M2g, float* __restrict__ M2){
  int t = threadIdx.x;
  if (t < 8){
    int j = t >> 2, h = t & 3;
    float s = 0.f;
    for (int c=0;c<128;c++) s += g_lin_e[j*512 + h*128 + c] * g_att_e[h*128 + c];
    M2g[j*4+h] = s;
  } else if (t < 32){
    int u = t - 8; int l = u >> 3, j = (u >> 2) & 1, h = u & 3;
    float s = 0.f;
    for (int c=0;c<128;c++) s += gat_lin_e[l*1024 + j*512 + h*128 + c] * gat_att_e[l*512 + h*128 + c];
    M2[l*8 + j*4 + h] = s;
  }
}

// ---------------- cluster GAT (tiny) ----------------
__global__ __launch_bounds__(64) void k_loop_c(const float* __restrict__ pair_cnt, const float* __restrict__ avg_attr,
                                               float* __restrict__ loop_c){
  int d = threadIdx.x;
  if (d >= NCLUS) return;
  float ic=0.f, l0=0.f, l1=0.f;
  for (int s=0;s<NCLUS;s++){
    int k = s*NCLUS + d;
    if (pair_cnt[k] > 0.f){ ic += 1.f; l0 += avg_attr[2*k]; l1 += avg_attr[2*k+1]; }
  }
  float inv = 1.f / fmaxf(ic, 1.f);
  loop_c[2*d] = l0*inv; loop_c[2*d+1] = l1*inv;
}
__global__ __launch_bounds__(256) void k_asc(const float* __restrict__ xh_c,
                     const float* __restrict__ g_att_s, const float* __restrict__ g_att_d,
                     float* __restrict__ a_s_c, float* __restrict__ a_d_c){
  int t = threadIdx.x;
  int s = t >> 2, h = t & 3;
  float ss=0.f, sd=0.f;
  for (int c=0;c<128;c++){
    float x = xh_c[s*512 + h*128 + c];
    ss += x * g_att_s[h*128 + c];
    sd += x * g_att_d[h*128 + c];
  }
  a_s_c[s*4+h] = ss; a_d_c[s*4+h] = sd;
}
__global__ __launch_bounds__(128) void k_clout(const float* __restrict__ a_s_c, const float* __restrict__ a_d_c,
                       const float* __restrict__ loop_c, const float* __restrict__ M2g,
                       const float* __restrict__ pair_cnt, const float* __restrict__ avg_attr,
                       const float* __restrict__ xh_c, const float* __restrict__ g_bias,
                       float* __restrict__ cl_out)
{
  int d = blockIdx.x;
  __shared__ float p[NCLUS*4];
  int t = threadIdx.x;
  if (t < NCLUS){
    int s = t;
    for (int h=0; h<4; ++h){
      float v;
      if (s == d){
        v = lrelu(a_s_c[d*4+h] + a_d_c[d*4+h] + loop_c[2*d]*M2g[h] + loop_c[2*d+1]*M2g[4+h]);
      } else if (pair_cnt[s*NCLUS+d] > 0.f){
        int k = s*NCLUS + d;
        v = lrelu(a_s_c[s*4+h] + a_d_c[d*4+h] + avg_attr[2*k]*M2g[h] + avg_attr[2*k+1]*M2g[4+h]);
      } else {
        v = -INFINITY;
      }
      p[s*4+h] = v;
    }
  }
  __syncthreads();
  if (t < 4){
    int h = t;
    float m = -INFINITY;
    for (int s=0;s<NCLUS;s++) m = fmaxf(m, p[s*4+h]);
    float sum = 0.f;
    for (int s=0;s<NCLUS;s++){
      float a = p[s*4+h];
      float e = (a == -INFINITY) ? 0.f : expf(a - m);
      p[s*4+h] = e; sum += e;
    }
    float inv = 1.f/sum;
    for (int s=0;s<NCLUS;s++) p[s*4+h] *= inv;
  }
  __syncthreads();
  int c = t;
  float acc = 0.f;
  for (int s=0;s<NCLUS;s++){
    #pragma unroll
    for (int h=0;h<4;h++) acc += p[s*4+h]*xh_c[s*512 + h*128 + c];
  }
  cl_out[d*128 + c] = 0.25f*acc + g_bias[c];
}

// Xcomb = Xc + cl_out[clus]; write bf16 only
__global__ __launch_bounds__(256) void k_xcomb(const float* __restrict__ Xc, const float* __restrict__ cl_out,
                                               const int* __restrict__ clus, unsigned short* __restrict__ outbf){
  int i = blockIdx.x*256 + threadIdx.x;
  int stride = gridDim.x*256;
  for (; i < NNODES*32; i += stride){
    int n = i >> 5, d4 = i & 31;
    float4 a = ((const float4*)Xc)[i];
    float4 b = ((const float4*)&cl_out[clus[n]*128])[d4];
    float4 r = f4add(a, b);
    uint2 u; u.x = pk2(r.x, r.y); u.y = pk2(r.z, r.w);
    ((uint2*)outbf)[i] = u;
  }
}

// ---------------- GAT edge aggregation (f16 xh, single node/wave, 2-deep pipeline, f16 out) ----------------
__global__ __launch_bounds__(256) void k_gat(const unsigned short* __restrict__ xh, const float* __restrict__ a_s,
                     const float* __restrict__ a_d, const float* __restrict__ eattr,
                     const int* __restrict__ offs, const int2* __restrict__ csr,
                     const float* __restrict__ la, const float* __restrict__ M2l,
                     const float* __restrict__ bias, __half* __restrict__ out)
{
  int wid  = (blockIdx.x*blockDim.x + threadIdx.x) >> 6;
  int lane = threadIdx.x & 63;
  int nw   = (gridDim.x*blockDim.x) >> 6;
  int h = lane >> 4;
  float m2a = M2l[h], m2b = M2l[4+h];
  for (int n = wid; n < NNODES; n += nw){
    int b0 = offs[n], b1 = offs[n+1];
    float asn = a_s[n*4+h];
    float adn = a_d[n*4+h];
    float inv = 1.f/fmaxf((float)(b1-b0), 1.f);
    float al = lrelu(asn + adn + la[2*n]*inv*m2a + la[2*n+1]*inv*m2b);
    float pl = __expf(al);
    float denom = pl;
    uint4 u0 = *reinterpret_cast<const uint4*>(xh + (size_t)n*512 + lane*8);
    __half2* x0 = reinterpret_cast<__half2*>(&u0);
    __half2 pl2 = __float2half2_rn(pl);
    __half2 acc0 = __hmul2(x0[0], pl2), acc1 = __hmul2(x0[1], pl2);
    __half2 acc2 = __hmul2(x0[2], pl2), acc3 = __hmul2(x0[3], pl2);
    int2 seA = make_int2(0,0), seB = make_int2(0,0);
    uint4 uA = make_uint4(0,0,0,0), uB = make_uint4(0,0,0,0);
    if (b0 < b1){
      seA = csr[b0];
      uA = *reinterpret_cast<const uint4*>(xh + (size_t)seA.x*512 + lane*8);
    }
    if (b0+1 < b1){
      seB = csr[b0+1];
      uB = *reinterpret_cast<const uint4*>(xh + (size_t)seB.x*512 + lane*8);
    }
    for (int idx=b0; idx<b1; ++idx){
      int s = seA.x, e = seA.y; uint4 u = uA;
      seA = seB; uA = uB;
      if (idx+2 < b1){
        seB = csr[idx+2];
        uB = *reinterpret_cast<const uint4*>(xh + (size_t)seB.x*512 + lane*8);
      }
      float2 ea = *reinterpret_cast<const float2*>(&eattr[2*e]);
      float al_e = lrelu(a_s[s*4+h] + adn + ea.x*m2a + ea.y*m2b);
      float pe = __expf(al_e);
      denom += pe;
      __half2 pe2 = __float2half2_rn(pe);
      __half2* y = reinterpret_cast<__half2*>(&u);
      acc0 = __hfma2(y[0], pe2, acc0);
      acc1 = __hfma2(y[1], pe2, acc1);
      acc2 = __hfma2(y[2], pe2, acc2);
      acc3 = __hfma2(y[3], pe2, acc3);
    }
    float sc = 0.25f/denom;
    float a[8];
    a[0]=__low2float(acc0); a[1]=__high2float(acc0);
    a[2]=__low2float(acc1); a[3]=__high2float(acc1);
    a[4]=__low2float(acc2); a[5]=__high2float(acc2);
    a[6]=__low2float(acc3); a[7]=__high2float(acc3);
    #pragma unroll
    for (int j=0;j<8;j++){
      a[j] *= sc;
      a[j] += __shfl_xor(a[j], 16);
      a[j] += __shfl_xor(a[j], 32);
    }
    if (lane < 16){
      int c = lane*8;
      float4 bb0 = *reinterpret_cast<const float4*>(&bias[c]);
      float4 bb1 = *reinterpret_cast<const float4*>(&bias[c+4]);
      __half2 hv[4];
      hv[0] = __floats2half2_rn(a[0]+bb0.x, a[1]+bb0.y);
      hv[1] = __floats2half2_rn(a[2]+bb0.z, a[3]+bb0.w);
      hv[2] = __floats2half2_rn(a[4]+bb1.x, a[5]+bb1.y);
      hv[3] = __floats2half2_rn(a[6]+bb1.z, a[7]+bb1.w);
      *reinterpret_cast<uint4*>(out + (size_t)n*128 + c) = *reinterpret_cast<uint4*>(hv);
    }
  }
}

// ---------------- graph norm (per-block partials, no atomics; f16 input) ----------------
__global__ __launch_bounds__(256) void k_colstat(const __half* __restrict__ X, float* __restrict__ part){
  int d = threadIdx.x & 127;
  int rg = threadIdx.x >> 7;
  float s1=0.f, s2=0.f;
  for (int n = blockIdx.x*2 + rg; n < NNODES; n += 512){
    float v = __half2float(X[(size_t)n*128 + d]);
    s1 += v; s2 = fmaf(v, v, s2);
  }
  __shared__ float sh[512];
  sh[threadIdx.x] = s1; sh[256+threadIdx.x] = s2;
  __syncthreads();
  if (threadIdx.x < 128){
    s1 = sh[threadIdx.x] + sh[threadIdx.x+128];
    s2 = sh[256+threadIdx.x] + sh[256+threadIdx.x+128];
    part[blockIdx.x*256 + d]       = s1;
    part[blockIdx.x*256 + 128 + d] = s2;
  }
}
__global__ __launch_bounds__(128) void k_finstat(const float* __restrict__ part,
                         const float* __restrict__ w, const float* __restrict__ b, const float* __restrict__ ms,
                         float* __restrict__ scaleA, float* __restrict__ shiftB){
  int d = threadIdx.x;
  float s1=0.f, s2=0.f;
  for (int bq=0; bq<256; bq++){ s1 += part[bq*256 + d]; s2 += part[bq*256 + 128 + d]; }
  float mean = s1 * (1.f/NNODES);
  float ex2  = s2 * (1.f/NNODES);
  float m = ms[d];
  float var = ex2 - m*mean*mean*(2.f - m);
  float sc = w[d] * rsqrtf(var + EPSV);
  scaleA[d] = sc;
  shiftB[d] = b[d] - sc*m*mean;
}
// norm + residual(bf16) + ELU; o is f16; write bf16 X (or f32 final output)
__global__ __launch_bounds__(256) void k_normelu(const __half* __restrict__ o, unsigned short* __restrict__ xb,
                         const float* __restrict__ scaleA, const float* __restrict__ shiftB,
                         float* __restrict__ fout){
  int i = blockIdx.x*256 + threadIdx.x;
  int stride = gridDim.x*256;
  for (; i < NNODES*32; i += stride){
    int d4 = i & 31;
    uint2 ou = ((const uint2*)o)[i];
    __half2* oh = reinterpret_cast<__half2*>(&ou);
    float o0 = __low2float(oh[0]), o1 = __high2float(oh[0]);
    float o2 = __low2float(oh[1]), o3 = __high2float(oh[1]);
    uint2 xu = ((const uint2*)xb)[i];
    float4 sc = ((const float4*)scaleA)[d4];
    float4 sh = ((const float4*)shiftB)[d4];
    float xi0 = __uint_as_float(xu.x<<16), xi1 = __uint_as_float(xu.x & 0xffff0000u);
    float xi2 = __uint_as_float(xu.y<<16), xi3 = __uint_as_float(xu.y & 0xffff0000u);
    float4 r; float y;
    y = fmaf(sc.x, o0, sh.x) + xi0; r.x = y > 0.f ? y : expm1f(y);
    y = fmaf(sc.y, o1, sh.y) + xi1; r.y = y > 0.f ? y : expm1f(y);
    y = fmaf(sc.z, o2, sh.z) + xi2; r.z = y > 0.f ? y : expm1f(y);
    y = fmaf(sc.w, o3, sh.w) + xi3; r.w = y > 0.f ? y : expm1f(y);
    if (fout){
      ((float4*)fout)[i] = r;
    } else {
      uint2 u; u.x = pk2(r.x, r.y); u.y = pk2(r.z, r.w);
      ((uint2*)xb)[i] = u;
    }
  }
}

// ---------------- host launch ----------------
extern "C" void kernel_launch(void* const* d_in, const int* in_sizes, int n_in,
                              void* d_out, int out_size, void* d_ws, size_t ws_size,
                              hipStream_t stream)
{
  const float* extra    = (const float*)d_in[0];
  const int*   ei       = (const int*)  d_in[1];
  const float* eattr    = (const float*)d_in[2];
  const int*   clus     = (const int*)  d_in[3];
  const float* user     = (const float*)d_in[4];
  const float* item     = (const float*)d_in[5];
  const float* W1       = (const float*)d_in[6];
  const float* b1       = (const float*)d_in[7];
  const float* W2       = (const float*)d_in[8];
  const float* b2       = (const float*)d_in[9];
  const float* gcnW     = (const float*)d_in[10];
  const float* gcnb     = (const float*)d_in[11];
  const float* g_lin    = (const float*)d_in[12];
  const float* g_lin_e  = (const float*)d_in[13];
  const float* g_att_s  = (const float*)d_in[14];
  const float* g_att_d  = (const float*)d_in[15];
  const float* g_att_e  = (const float*)d_in[16];
  const float* g_bias   = (const float*)d_in[17];
  const float* gat_lin  = (const float*)d_in[18];
  const float* gat_lin_e= (const float*)d_in[19];
  const float* gat_att_s= (const float*)d_in[20];
  const float* gat_att_d= (const float*)d_in[21];
  const float* gat_att_e= (const float*)d_in[22];
  const float* gat_bias = (const float*)d_in[23];
  const float* nw_      = (const float*)d_in[24];
  const float* nb_      = (const float*)d_in[25];
  const float* nms_     = (const float*)d_in[26];

  char* ws = (char*)d_ws;
  size_t off = 0;
  auto alloc = [&](size_t bytes)->char*{
    char* p = ws + off;
    off += (bytes + 255) & ~size_t(255);
    return p;
  };

  float* bufX = (float*)alloc((size_t)NNODES*128*4);
  float* bufY = (float*)alloc((size_t)NNODES*128*4);
  float* bufZ = (float*)alloc((size_t)NNODES*128*4);
  // shared "big" region (disjoint lifetimes):
  //   [0,20.5MB)    Xbf   (live from k_xcomb to end)
  //   [22,104MB)    XHf   (live during GAT layers only)
  //   [22,28.3MB)   pcb/pa0b/pa1b (pairhist phase, before MLP)
  //   [22,37.4MB)   Hbf   (MLP phase only)
  //   [40,53.1MB)   ppart (pool phase, before layers)
  char* big = alloc((size_t)112*1024*1024);
  unsigned short* Xbf   = (unsigned short*)big;
  unsigned short* XHf   = (unsigned short*)(big + (size_t)22*1024*1024);
  unsigned short* Hbf   = (unsigned short*)(big + (size_t)22*1024*1024);
  float* pcb  = (float*)(big + (size_t)22*1024*1024);
  float* pa0b = pcb  + 4096*128;
  float* pa1b = pa0b + 4096*128;
  float* ppart = (float*)(big + (size_t)40*1024*1024);
  int* offs   = (int*)alloc((NNODES+1)*4);
  int* ioffs  = (int*)alloc((NNODES+1)*4);
  int* bsum   = (int*)alloc(1024*4);
  int* bsum2  = (int*)alloc(1024*4);
  int2* csr   = (int2*)alloc((size_t)NEDGES*8);
  int* csr2   = (int*)alloc((size_t)NEDGES*4);
  float* a_s  = (float*)alloc((size_t)NNODES*4*4);
  float* a_d  = (float*)alloc((size_t)NNODES*4*4);
  // zeroed-per-call region (single memset)
  char* zero0 = ws + off;
  int*   cnt      = (int*)  alloc((size_t)NNODES*4);
  int*   intra    = (int*)  alloc((size_t)NNODES*4);
  int*   cursor   = (int*)  alloc((size_t)NNODES*4);
  int*   cursor2  = (int*)  alloc((size_t)NNODES*4);
  int*   csize    = (int*)  alloc(256*4);
  float* la       = (float*)alloc((size_t)NNODES*2*4);
  size_t zbytes = (size_t)((ws + off) - zero0);
  // small buffers
  float* pooled= (float*)alloc(8192*4);
  float* M2g   = (float*)alloc(8*4);
  float* M2    = (float*)alloc(24*4);
  float* pair_cnt = (float*)alloc(4096*4);
  float* avg_attr = (float*)alloc(8192*4);
  float* loop_c   = (float*)alloc(128*4);
  float* xh_c     = (float*)alloc(64*512*4);
  float* a_s_c    = (float*)alloc(256*4);
  float* a_d_c    = (float*)alloc(256*4);
  float* cl_out   = (float*)alloc(64*128*4);
  float* colpart  = (float*)alloc(256*256*4);
  float* scaleA   = (float*)alloc(128*4);
  float* shiftB   = (float*)alloc(128*4);
  unsigned short* W1t  = (unsigned short*)alloc((size_t)896*256*2);
  unsigned short* W2t  = (unsigned short*)alloc((size_t)256*128*2);
  unsigned short* gcnWt= (unsigned short*)alloc((size_t)128*128*2);
  unsigned short* glt  = (unsigned short*)alloc((size_t)3*128*512*2);
  if (off > ws_size) return;

  hipMemsetAsync(zero0, 0, zbytes, stream);

  const int NB = (NNODES+255)/256;
  // phase 0: pair hist + cnt/intra, reduce; dual scans; fused fill (CSR + intra-CSR + la)
  k_pairhist<<<128, 1024, 0, stream>>>(ei, eattr, clus, cnt, intra, pcb, pa0b, pa1b);
  k_pairreduce<<<64, 64, 0, stream>>>(pcb, pa0b, pa1b, pair_cnt, avg_attr);
  k_scan_block<<<NB, 256, 0, stream>>>(cnt, offs, bsum, NNODES, clus, csize);
  k_scan_block<<<NB, 256, 0, stream>>>(intra, ioffs, bsum2, NNODES, nullptr, nullptr);
  k_scan_bsum<<<1, 512, 0, stream>>>(bsum, NB);
  k_scan_bsum<<<1, 512, 0, stream>>>(bsum2, NB);
  k_scan_add<<<NB, 256, 0, stream>>>(offs, bsum, NNODES, NEDGES);
  k_scan_add<<<NB, 256, 0, stream>>>(ioffs, bsum2, NNODES, 0);
  k_fill_csr<<<(NEDGES+255)/256, 256, 0, stream>>>(ei, eattr, clus, offs, ioffs,
                                                   cursor, cursor2, csr, csr2, la);

  // small precomputes + weight conversions
  k_m2<<<1, 64, 0, stream>>>(g_lin_e, g_att_e, gat_lin_e, gat_att_e, M2g, M2);
  k_wtall<<<(475136+255)/256, 256, 0, stream>>>(W1, W2, gcnW, gat_lin, W1t, W2t, gcnWt, glt);

  // enrichment MLP (bf16 MFMA, f32-A fused conversion); Hbf reuses dead pairhist region
  {
    dim3 g1((N_ITEMS+127)/128, 2);
    k_mgemm<1,1,1,1,1,0><<<g1, 256, 0, stream>>>((const void*)item, extra, W1t, b1, (void*)Hbf,
                                                 N_ITEMS, 256, 896, 128, nullptr, nullptr, nullptr, nullptr);
    dim3 g2((N_ITEMS+127)/128, 1);
    k_mgemm<0,0,0,0,1,0><<<g2, 256, 0, stream>>>((const void*)Hbf, nullptr, W2t, b2,
                                                 (void*)(bufX + (size_t)N_USERS*128),
                                                 N_ITEMS, 128, 256, 0, nullptr, nullptr, nullptr, nullptr);
  }
  hipMemcpyAsync(bufX, user, (size_t)N_USERS*128*4, hipMemcpyDeviceToDevice, stream);

  // cluster GCN: XW (f16) = X @ gcnW; aggregate over intra-CSR only
  {
    dim3 g3((NNODES+127)/128, 1);
    k_mgemm<1,0,2,0,0,0><<<g3, 256, 0, stream>>>((const void*)bufX, nullptr, gcnWt, nullptr, (void*)bufY,
                                                 NNODES, 128, 128, 0, nullptr, nullptr, nullptr, nullptr);
  }
  k_gcn<<<5000, 256, 0, stream>>>((const unsigned short*)bufY, ioffs, csr2, intra, gcnb, bufZ);

  // pooling (LDS partials) + cluster GAT
  k_pool1<<<400, 256, 0, stream>>>(bufZ, clus, ppart);
  k_pool2<<<32, 256, 0, stream>>>(ppart, csize, pooled);
  {
    dim3 g4(1, 4);
    k_sgemm<0,0><<<g4, 256, 0, stream>>>(pooled, nullptr, g_lin, nullptr, xh_c, 64, 512, 128, 0);
  }
  k_loop_c<<<1, 64, 0, stream>>>(pair_cnt, avg_attr, loop_c);
  k_asc<<<1, 256, 0, stream>>>(xh_c, g_att_s, g_att_d, a_s_c, a_d_c);
  k_clout<<<64, 128, 0, stream>>>(a_s_c, a_d_c, loop_c, M2g, pair_cnt, avg_attr, xh_c, g_bias, cl_out);
  k_xcomb<<<1280, 256, 0, stream>>>(bufZ, cl_out, clus, Xbf);

  // 3 GAT layers (X in Xbf bf16; xh in f16; a_s/a_d fused in GEMM epilogue; single-node k_gat)
  for (int l = 0; l < 3; ++l){
    dim3 gx((NNODES+127)/128, 4);
    k_mgemm<0,0,2,0,0,1><<<gx, 256, 0, stream>>>((const void*)Xbf, nullptr, glt + (size_t)l*65536, nullptr,
                                                 (void*)XHf, NNODES, 512, 128, 0,
                                                 gat_att_s + l*512, gat_att_d + l*512, a_s, a_d);
    k_gat<<<20000, 256, 0, stream>>>(XHf, a_s, a_d, eattr, offs, csr, la,
                                     M2 + l*8, gat_bias + l*128, (__half*)bufY);
    k_colstat<<<256, 256, 0, stream>>>((const __half*)bufY, colpart);
    k_finstat<<<1, 128, 0, stream>>>(colpart, nw_ + l*128, nb_ + l*128, nms_ + l*128, scaleA, shiftB);
    k_normelu<<<1280, 256, 0, stream>>>((const __half*)bufY, Xbf, scaleA, shiftB, (l==2) ? (float*)d_out : nullptr);
  }
}

// Round 12
// 1400.387 us; speedup vs baseline: 1.0455x; 1.0325x over previous
//
#include <hip/hip_runtime.h>
#include <hip/hip_fp16.h>
#include <math.h>

#define N_USERS 50000
#define N_ITEMS 30000
#define NNODES  80000
#define NEDGES  640000
#define NCLUS   64
#define NEG     0.2f
#define EPSV    1e-5f

typedef __attribute__((ext_vector_type(8))) short bf16x8;
typedef __attribute__((ext_vector_type(4))) float f32x4;

__device__ __forceinline__ float lrelu(float x){ return x > 0.f ? x : NEG*x; }

__device__ __forceinline__ unsigned short f2bf(float f){
  unsigned u = __float_as_uint(f);
  u += 0x7fffu + ((u>>16)&1u);
  return (unsigned short)(u>>16);
}
__device__ __forceinline__ unsigned pk2(float lo, float hi){
  return (unsigned)f2bf(lo) | ((unsigned)f2bf(hi) << 16);
}
__device__ __forceinline__ float4 f4add(float4 a, float4 b){
  return make_float4(a.x+b.x, a.y+b.y, a.z+b.z, a.w+b.w);
}

// ---------------- phase 0: pair histogram (LDS-aggregated, 1024-thread blocks) ----------------
__global__ __launch_bounds__(1024) void k_pairhist(
    const int* __restrict__ ei, const float* __restrict__ eattr, const int* __restrict__ clus,
    int* __restrict__ cnt, int* __restrict__ intra,
    float* __restrict__ pcb, float* __restrict__ pa0b, float* __restrict__ pa1b)
{
  __shared__ float pc[4096];
  __shared__ float pa0[4096];
  __shared__ float pa1[4096];
  for (int i=threadIdx.x; i<4096; i+=1024){ pc[i]=0.f; pa0[i]=0.f; pa1[i]=0.f; }
  __syncthreads();
  for (int e = blockIdx.x*1024 + threadIdx.x; e < NEDGES; e += 128*1024){
    int s = ei[e], d = ei[NEDGES+e];
    int cu = clus[s], cv = clus[d];
    atomicAdd(&cnt[d], 1);
    if (cu == cv) { atomicAdd(&intra[d], 1); }
    else {
      float2 a = *reinterpret_cast<const float2*>(&eattr[2*e]);
      int k = cu*NCLUS + cv;
      atomicAdd(&pc[k], 1.f);
      atomicAdd(&pa0[k], a.x);
      atomicAdd(&pa1[k], a.y);
    }
  }
  __syncthreads();
  int b = blockIdx.x;
  for (int i=threadIdx.x; i<4096; i+=1024){
    pcb [i*128 + b] = pc[i];
    pa0b[i*128 + b] = pa0[i];
    pa1b[i*128 + b] = pa1[i];
  }
}

__global__ __launch_bounds__(64) void k_pairreduce(
    const float* __restrict__ pcb, const float* __restrict__ pa0b, const float* __restrict__ pa1b,
    float* __restrict__ pair_cnt, float* __restrict__ avg_attr)
{
  int i = blockIdx.x*64 + threadIdx.x;  // 4096 total over grid 64
  float c=0.f, s0=0.f, s1=0.f;
  const float4* P0 = (const float4*)(pcb  + (size_t)i*128);
  const float4* P1 = (const float4*)(pa0b + (size_t)i*128);
  const float4* P2 = (const float4*)(pa1b + (size_t)i*128);
  for (int b=0;b<32;b++){
    float4 v0=P0[b], v1=P1[b], v2=P2[b];
    c  += v0.x+v0.y+v0.z+v0.w;
    s0 += v1.x+v1.y+v1.z+v1.w;
    s1 += v2.x+v2.y+v2.z+v2.w;
  }
  pair_cnt[i] = c;
  float inv = 1.f/fmaxf(c, 1.f);
  avg_attr[2*i]   = s0*inv;
  avg_attr[2*i+1] = s1*inv;
}

// scan block (+ optional node histogram)
__global__ __launch_bounds__(256) void k_scan_block(const int* __restrict__ in, int* __restrict__ out,
                                                    int* __restrict__ bsum, int n,
                                                    const int* __restrict__ clus, int* __restrict__ csize){
  __shared__ int buf[256];
  int i = blockIdx.x*256 + threadIdx.x;
  int v = (i < n) ? in[i] : 0;
  if (csize && i < n) atomicAdd(&csize[clus[i]], 1);
  buf[threadIdx.x] = v; __syncthreads();
  for (int off=1; off<256; off<<=1){
    int t = (threadIdx.x>=off) ? buf[threadIdx.x-off] : 0;
    __syncthreads();
    buf[threadIdx.x] += t;
    __syncthreads();
  }
  if (i < n) out[i] = buf[threadIdx.x] - v;
  if (threadIdx.x == 255) bsum[blockIdx.x] = buf[255];
}

__global__ __launch_bounds__(512) void k_scan_bsum(int* __restrict__ bsum, int nb){
  __shared__ int buf[512];
  int v = (threadIdx.x < nb) ? bsum[threadIdx.x] : 0;
  buf[threadIdx.x] = v; __syncthreads();
  for (int off=1; off<512; off<<=1){
    int t = (threadIdx.x>=off) ? buf[threadIdx.x-off] : 0;
    __syncthreads();
    buf[threadIdx.x] += t;
    __syncthreads();
  }
  if (threadIdx.x < nb) bsum[threadIdx.x] = buf[threadIdx.x] - v;
}

__global__ __launch_bounds__(256) void k_scan_add(int* __restrict__ out, const int* __restrict__ bsum,
                                                  int n, int total){
  int i = blockIdx.x*256 + threadIdx.x;
  if (i < n) out[i] += bsum[i>>8];
  if (i == 0) out[n] = total;
}

// fill main CSR + intra CSR (no atomics on float data)
__global__ __launch_bounds__(256) void k_fill_csr(const int* __restrict__ ei, const int* __restrict__ clus,
                                                  const int* __restrict__ offs, const int* __restrict__ ioffs,
                                                  int* __restrict__ cursor, int* __restrict__ cursor2,
                                                  int2* __restrict__ csr, int* __restrict__ csr2){
  int e = blockIdx.x*256 + threadIdx.x;
  if (e >= NEDGES) return;
  int s = ei[e], d = ei[NEDGES+e];
  int pos = offs[d] + atomicAdd(&cursor[d], 1);
  csr[pos] = make_int2(s, e);
  if (clus[s] == clus[d]){
    int p2 = ioffs[d] + atomicAdd(&cursor2[d], 1);
    csr2[p2] = s;
  }
}

// per-node mean edge-attr (self-loop fill), from CSR
__global__ __launch_bounds__(256) void k_loopattr(const int* __restrict__ offs, const int2* __restrict__ csr,
                                                  const float* __restrict__ eattr, float* __restrict__ la){
  int n = blockIdx.x*256 + threadIdx.x;
  if (n >= NNODES) return;
  int b0 = offs[n], b1 = offs[n+1];
  float s0=0.f, s1=0.f;
  for (int i=b0; i<b1; ++i){
    int e = csr[i].y;
    float2 a = *reinterpret_cast<const float2*>(&eattr[2*e]);
    s0 += a.x; s1 += a.y;
  }
  float inv = 1.f/fmaxf((float)(b1-b0), 1.f);
  la[2*n] = s0*inv; la[2*n+1] = s1*inv;
}

// ---------------- all weight transposes+converts in one kernel ----------------
__global__ __launch_bounds__(256) void k_wtall(const float* __restrict__ W1, const float* __restrict__ W2,
                       const float* __restrict__ gcnW, const float* __restrict__ gat_lin,
                       unsigned short* __restrict__ W1t, unsigned short* __restrict__ W2t,
                       unsigned short* __restrict__ gcnWt, unsigned short* __restrict__ glt){
  int i = blockIdx.x*256 + threadIdx.x;
  if (i < 229376){            // W1: K=896, N=256
    int n = i/896, k = i - n*896;
    W1t[i] = f2bf(W1[(size_t)k*256 + n]);
  } else if (i < 262144){     // W2: K=256, N=128
    int j = i - 229376; int n = j/256, k = j - n*256;
    W2t[j] = f2bf(W2[(size_t)k*128 + n]);
  } else if (i < 278528){     // gcnW: 128x128
    int j = i - 262144; int n = j/128, k = j - n*128;
    gcnWt[j] = f2bf(gcnW[(size_t)k*128 + n]);
  } else if (i < 475136){     // gat_lin: 3 x (K=128, N=512)
    int j = i - 278528; int l = j >> 16; int r = j & 65535; int n = r/128, k = r - n*128;
    glt[j] = f2bf(gat_lin[(size_t)l*65536 + (size_t)k*512 + n]);
  }
}

// ---------------- bf16 MFMA GEMM: C = act(A @ Bt^T + bias) ----------------
// AF32: A is f32 (converted during staging); CONCAT: A|A2 split at K1.
// OUT: 0=f32, 1=bf16, 2=f16
// ASD: also emit a_s/a_d per-row dots with attS/attD (blockIdx.y = head).
template<int AF32, int CONCAT, int OUT, int RELU, int BIAS, int ASD>
__global__ __launch_bounds__(256)
void k_mgemm(const void* __restrict__ Av, const float* __restrict__ A2,
             const unsigned short* __restrict__ Bt, const float* __restrict__ bias,
             void* __restrict__ Cv, int M, int N, int K, int K1,
             const float* __restrict__ attS, const float* __restrict__ attD,
             float* __restrict__ oas, float* __restrict__ oad)
{
  __shared__ unsigned short As[128*64];
  __shared__ unsigned short Bs[128*64];
  __shared__ float sAs[2][128], sAd[2][128];
  const int tid = threadIdx.x;
  const int lane = tid & 63, w = tid >> 6;
  const int row0 = blockIdx.x*128, col0 = blockIdx.y*128;
  const int wm = w >> 1, wn = w & 1;
  const int l15 = lane & 15, l4 = lane >> 4;
  f32x4 acc[4][4];
  #pragma unroll
  for (int i=0;i<4;i++)
    #pragma unroll
    for (int n=0;n<4;n++) acc[i][n] = (f32x4){0.f,0.f,0.f,0.f};

  const int rr0 = w*32 + (lane>>3);
  const int cA = lane & 7;

  for (int kt = 0; kt < K; kt += 64){
    uint4 ra[4], rb[4];
    #pragma unroll
    for (int i=0;i<4;i++){
      int rr = rr0 + i*8;
      int ga = row0 + rr; ga = (ga < M) ? ga : (M-1);
      int gb = col0 + rr; gb = (gb < N) ? gb : (N-1);
      int gk = kt + cA*8;
      if (AF32){
        const float* Af = (const float*)Av;
        const float* src;
        if (CONCAT && gk >= K1) src = A2 + (size_t)ga*(K-K1) + (gk - K1);
        else                    src = Af + (size_t)ga*(CONCAT ? K1 : K) + gk;
        float4 f0 = ((const float4*)src)[0];
        float4 f1 = ((const float4*)src)[1];
        ra[i] = make_uint4(pk2(f0.x,f0.y), pk2(f0.z,f0.w), pk2(f1.x,f1.y), pk2(f1.z,f1.w));
      } else {
        ra[i] = *reinterpret_cast<const uint4*>((const unsigned short*)Av + (size_t)ga*K + gk);
      }
      rb[i] = *reinterpret_cast<const uint4*>(Bt + (size_t)gb*K + gk);
    }
    __syncthreads();
    #pragma unroll
    for (int i=0;i<4;i++){
      int rr = rr0 + i*8;
      int ch = cA ^ (rr & 7);
      *reinterpret_cast<uint4*>(&As[rr*64 + ch*8]) = ra[i];
      *reinterpret_cast<uint4*>(&Bs[rr*64 + ch*8]) = rb[i];
    }
    __syncthreads();
    #pragma unroll
    for (int k0=0;k0<2;k0++){
      bf16x8 af[4], bff[4];
      #pragma unroll
      for (int i=0;i<4;i++){
        int row = wm*64 + i*16 + l15;
        int ch = (k0*4 + l4) ^ (row & 7);
        af[i] = *reinterpret_cast<const bf16x8*>(&As[row*64 + ch*8]);
      }
      #pragma unroll
      for (int n=0;n<4;n++){
        int row = wn*64 + n*16 + l15;
        int ch = (k0*4 + l4) ^ (row & 7);
        bff[n] = *reinterpret_cast<const bf16x8*>(&Bs[row*64 + ch*8]);
      }
      #pragma unroll
      for (int i=0;i<4;i++)
        #pragma unroll
        for (int n=0;n<4;n++)
          acc[i][n] = __builtin_amdgcn_mfma_f32_16x16x32_bf16(af[i], bff[n], acc[i][n], 0, 0, 0);
    }
  }
  // C store
  #pragma unroll
  for (int i=0;i<4;i++){
    int rowb = row0 + wm*64 + i*16 + l4*4;
    #pragma unroll
    for (int n=0;n<4;n++){
      int col = col0 + wn*64 + n*16 + l15;
      float bv = BIAS ? bias[col] : 0.f;
      #pragma unroll
      for (int r=0;r<4;r++){
        int row = rowb + r;
        if (row < M){
          float y = acc[i][n][r] + bv;
          if (RELU) y = fmaxf(y, 0.f);
          if (OUT == 1)      ((unsigned short*)Cv)[(size_t)row*N + col] = f2bf(y);
          else if (OUT == 2) ((__half*)Cv)[(size_t)row*N + col] = __float2half(y);
          else               ((float*)Cv)[(size_t)row*N + col] = y;
        }
      }
    }
  }
  if (ASD){
    const float* aSb = attS + (size_t)blockIdx.y*128;
    const float* aDb = attD + (size_t)blockIdx.y*128;
    float aS[4], aD[4];
    #pragma unroll
    for (int n=0;n<4;n++){
      int c = wn*64 + n*16 + l15;
      aS[n] = aSb[c]; aD[n] = aDb[c];
    }
    float ps[4][4], pd[4][4];
    #pragma unroll
    for (int i=0;i<4;i++)
      #pragma unroll
      for (int r=0;r<4;r++){
        float s=0.f, d=0.f;
        #pragma unroll
        for (int n=0;n<4;n++){
          s = fmaf(acc[i][n][r], aS[n], s);
          d = fmaf(acc[i][n][r], aD[n], d);
        }
        ps[i][r]=s; pd[i][r]=d;
      }
    #pragma unroll
    for (int m=1;m<16;m<<=1){
      #pragma unroll
      for (int i=0;i<4;i++)
        #pragma unroll
        for (int r=0;r<4;r++){
          ps[i][r] += __shfl_xor(ps[i][r], m);
          pd[i][r] += __shfl_xor(pd[i][r], m);
        }
    }
    if (l15 == 0){
      #pragma unroll
      for (int i=0;i<4;i++)
        #pragma unroll
        for (int r=0;r<4;r++){
          int rl = wm*64 + i*16 + l4*4 + r;
          sAs[wn][rl] = ps[i][r];
          sAd[wn][rl] = pd[i][r];
        }
    }
    __syncthreads();
    if (tid < 128){
      int row = row0 + tid;
      if (row < M){
        int head = blockIdx.y;
        oas[(size_t)row*4 + head] = sAs[0][tid] + sAs[1][tid];
        oad[(size_t)row*4 + head] = sAd[0][tid] + sAd[1][tid];
      }
    }
  }
}

// ---------------- f32 SGEMM (tiny pooled GEMM only) ----------------
template<int CONCAT, int ACT>
__global__ __launch_bounds__(256)
void k_sgemm(const float* __restrict__ A, const float* __restrict__ A2,
             const float* __restrict__ B, const float* __restrict__ bias,
             float* __restrict__ C, int M, int N, int K, int K1)
{
  __shared__ float As[8][128];
  __shared__ float Bs[8][128];
  int row0 = blockIdx.x*128, col0 = blockIdx.y*128;
  int tid = threadIdx.x;
  int tx = tid & 15, ty = tid >> 4;
  float acc[8][8];
  #pragma unroll
  for (int i=0;i<8;i++)
    #pragma unroll
    for (int j=0;j<8;j++) acc[i][j]=0.f;

  int arow = tid >> 1, acol = (tid & 1)*4;
  int brow = tid >> 5, bcol = (tid & 31)*4;
  int K2 = K - K1;

  for (int k0=0; k0<K; k0+=8){
    float4 av = make_float4(0.f,0.f,0.f,0.f);
    int gr = row0 + arow, gk = k0 + acol;
    if (gr < M){
      if (CONCAT){
        if (gk < K1) av = *reinterpret_cast<const float4*>(&A [(size_t)gr*K1 + gk]);
        else         av = *reinterpret_cast<const float4*>(&A2[(size_t)gr*K2 + (gk-K1)]);
      } else {
        av = *reinterpret_cast<const float4*>(&A[(size_t)gr*K + gk]);
      }
    }
    As[acol+0][arow]=av.x; As[acol+1][arow]=av.y; As[acol+2][arow]=av.z; As[acol+3][arow]=av.w;
    float4 bv = *reinterpret_cast<const float4*>(&B[(size_t)(k0+brow)*N + col0 + bcol]);
    *reinterpret_cast<float4*>(&Bs[brow][bcol]) = bv;
    __syncthreads();
    #pragma unroll
    for (int kk=0; kk<8; ++kk){
      float a[8], b[8];
      *(float4*)&a[0] = *(float4*)&As[kk][ty*8];
      *(float4*)&a[4] = *(float4*)&As[kk][ty*8+4];
      *(float4*)&b[0] = *(float4*)&Bs[kk][tx*8];
      *(float4*)&b[4] = *(float4*)&Bs[kk][tx*8+4];
      #pragma unroll
      for (int i=0;i<8;i++)
        #pragma unroll
        for (int j=0;j<8;j++) acc[i][j] = fmaf(a[i], b[j], acc[i][j]);
    }
    __syncthreads();
  }
  #pragma unroll
  for (int i=0;i<8;i++){
    int r = row0 + ty*8 + i;
    if (r >= M) continue;
    #pragma unroll
    for (int j4=0;j4<2;j4++){
      int c = col0 + tx*8 + j4*4;
      float4 v = make_float4(acc[i][j4*4], acc[i][j4*4+1], acc[i][j4*4+2], acc[i][j4*4+3]);
      if (bias){
        float4 bb = *reinterpret_cast<const float4*>(&bias[c]);
        v = f4add(v, bb);
      }
      if (ACT == 1){
        v.x=fmaxf(v.x,0.f); v.y=fmaxf(v.y,0.f); v.z=fmaxf(v.z,0.f); v.w=fmaxf(v.w,0.f);
      }
      *reinterpret_cast<float4*>(&C[(size_t)r*N + c]) = v;
    }
  }
}

// ---------------- GCN aggregation (intra-CSR: only intra-cluster edges) ----------------
__global__ __launch_bounds__(256) void k_gcn(const unsigned short* __restrict__ XWh, const int* __restrict__ ioffs,
                      const int* __restrict__ csr2, const int* __restrict__ intra,
                      const float* __restrict__ gcn_b, float* __restrict__ Xc)
{
  int wid  = (blockIdx.x*blockDim.x + threadIdx.x) >> 6;
  int lane = threadIdx.x & 63;
  int nw   = (gridDim.x*blockDim.x) >> 6;
  for (int n = wid; n < NNODES; n += nw){
    int cntn = intra[n];
    float deg = 1.f + (float)cntn;
    float dinv_n = rsqrtf(deg);
    __half2 hx = *reinterpret_cast<const __half2*>(XWh + (size_t)n*128 + lane*2);
    float2 acc;
    acc.x = __low2float(hx)/deg; acc.y = __high2float(hx)/deg;
    int io0 = ioffs[n];
    for (int j=0; j<cntn; ++j){
      int s = csr2[io0+j];
      float w = dinv_n * rsqrtf(1.f + (float)intra[s]);
      __half2 hs = *reinterpret_cast<const __half2*>(XWh + (size_t)s*128 + lane*2);
      acc.x = fmaf(w, __low2float(hs), acc.x);
      acc.y = fmaf(w, __high2float(hs), acc.y);
    }
    float2 bb = *reinterpret_cast<const float2*>(&gcn_b[lane*2]);
    acc.x += bb.x; acc.y += bb.y;
    *reinterpret_cast<float2*>(&Xc[(size_t)n*128 + lane*2]) = acc;
  }
}

// ---------------- cluster pooling: LDS partials + reduce ----------------
__global__ __launch_bounds__(256) void k_pool1(const float* __restrict__ Xc, const int* __restrict__ clus,
                                               float* __restrict__ part){
  __shared__ float lp[8192];
  for (int i=threadIdx.x; i<8192; i+=256) lp[i]=0.f;
  __syncthreads();
  int d = threadIdx.x & 127, rg = threadIdx.x >> 7;
  int n0 = blockIdx.x*200;
  for (int n = n0+rg; n < n0+200; n += 2){
    int c = clus[n];
    atomicAdd(&lp[c*128 + d], Xc[(size_t)n*128 + d]);
  }
  __syncthreads();
  for (int i=threadIdx.x; i<8192; i+=256) part[(size_t)blockIdx.x*8192 + i] = lp[i];
}
__global__ __launch_bounds__(256) void k_pool2(const float* __restrict__ part, const int* __restrict__ csize,
                                               float* __restrict__ pooled){
  int i = blockIdx.x*256 + threadIdx.x; // 8192
  float s = 0.f;
  for (int b=0;b<400;b++) s += part[(size_t)b*8192 + i];
  pooled[i] = s / fmaxf((float)csize[i>>7], 1.f);
}

// ---------------- small precomputes ----------------
__global__ __launch_bounds__(64) void k_m2(const float* __restrict__ g_lin_e, const float* __restrict__ g_att_e,
                    const float* __restrict__ gat_lin_e, const float* __restrict__ gat_att_e,
                    float* __restrict__ M2g, float* __restrict__ M2){
  int t = threadIdx.x;
  if (t < 8){
    int j = t >> 2, h = t & 3;
    float s = 0.f;
    for (int c=0;c<128;c++) s += g_lin_e[j*512 + h*128 + c] * g_att_e[h*128 + c];
    M2g[j*4+h] = s;
  } else if (t < 32){
    int u = t - 8; int l = u >> 3, j = (u >> 2) & 1, h = u & 3;
    float s = 0.f;
    for (int c=0;c<128;c++) s += gat_lin_e[l*1024 + j*512 + h*128 + c] * gat_att_e[l*512 + h*128 + c];
    M2[l*8 + j*4 + h] = s;
  }
}

// ---------------- cluster GAT (tiny) ----------------
__global__ __launch_bounds__(64) void k_loop_c(const float* __restrict__ pair_cnt, const float* __restrict__ avg_attr,
                                               float* __restrict__ loop_c){
  int d = threadIdx.x;
  if (d >= NCLUS) return;
  float ic=0.f, l0=0.f, l1=0.f;
  for (int s=0;s<NCLUS;s++){
    int k = s*NCLUS + d;
    if (pair_cnt[k] > 0.f){ ic += 1.f; l0 += avg_attr[2*k]; l1 += avg_attr[2*k+1]; }
  }
  float inv = 1.f / fmaxf(ic, 1.f);
  loop_c[2*d] = l0*inv; loop_c[2*d+1] = l1*inv;
}
__global__ __launch_bounds__(256) void k_asc(const float* __restrict__ xh_c,
                     const float* __restrict__ g_att_s, const float* __restrict__ g_att_d,
                     float* __restrict__ a_s_c, float* __restrict__ a_d_c){
  int t = threadIdx.x;
  int s = t >> 2, h = t & 3;
  float ss=0.f, sd=0.f;
  for (int c=0;c<128;c++){
    float x = xh_c[s*512 + h*128 + c];
    ss += x * g_att_s[h*128 + c];
    sd += x * g_att_d[h*128 + c];
  }
  a_s_c[s*4+h] = ss; a_d_c[s*4+h] = sd;
}
__global__ __launch_bounds__(128) void k_clout(const float* __restrict__ a_s_c, const float* __restrict__ a_d_c,
                       const float* __restrict__ loop_c, const float* __restrict__ M2g,
                       const float* __restrict__ pair_cnt, const float* __restrict__ avg_attr,
                       const float* __restrict__ xh_c, const float* __restrict__ g_bias,
                       float* __restrict__ cl_out)
{
  int d = blockIdx.x;
  __shared__ float p[NCLUS*4];
  int t = threadIdx.x;
  if (t < NCLUS){
    int s = t;
    for (int h=0; h<4; ++h){
      float v;
      if (s == d){
        v = lrelu(a_s_c[d*4+h] + a_d_c[d*4+h] + loop_c[2*d]*M2g[h] + loop_c[2*d+1]*M2g[4+h]);
      } else if (pair_cnt[s*NCLUS+d] > 0.f){
        int k = s*NCLUS + d;
        v = lrelu(a_s_c[s*4+h] + a_d_c[d*4+h] + avg_attr[2*k]*M2g[h] + avg_attr[2*k+1]*M2g[4+h]);
      } else {
        v = -INFINITY;
      }
      p[s*4+h] = v;
    }
  }
  __syncthreads();
  if (t < 4){
    int h = t;
    float m = -INFINITY;
    for (int s=0;s<NCLUS;s++) m = fmaxf(m, p[s*4+h]);
    float sum = 0.f;
    for (int s=0;s<NCLUS;s++){
      float a = p[s*4+h];
      float e = (a == -INFINITY) ? 0.f : expf(a - m);
      p[s*4+h] = e; sum += e;
    }
    float inv = 1.f/sum;
    for (int s=0;s<NCLUS;s++) p[s*4+h] *= inv;
  }
  __syncthreads();
  int c = t;
  float acc = 0.f;
  for (int s=0;s<NCLUS;s++){
    #pragma unroll
    for (int h=0;h<4;h++) acc += p[s*4+h]*xh_c[s*512 + h*128 + c];
  }
  cl_out[d*128 + c] = 0.25f*acc + g_bias[c];
}

// Xcomb = Xc + cl_out[clus]; write bf16 only
__global__ __launch_bounds__(256) void k_xcomb(const float* __restrict__ Xc, const float* __restrict__ cl_out,
                                               const int* __restrict__ clus, unsigned short* __restrict__ outbf){
  int i = blockIdx.x*256 + threadIdx.x;
  int stride = gridDim.x*256;
  for (; i < NNODES*32; i += stride){
    int n = i >> 5, d4 = i & 31;
    float4 a = ((const float4*)Xc)[i];
    float4 b = ((const float4*)&cl_out[clus[n]*128])[d4];
    float4 r = f4add(a, b);
    uint2 u; u.x = pk2(r.x, r.y); u.y = pk2(r.z, r.w);
    ((uint2*)outbf)[i] = u;
  }
}

// ---------------- GAT edge aggregation (f16 xh, 2-deep pipeline, f16 out) ----------------
__global__ __launch_bounds__(256) void k_gat(const unsigned short* __restrict__ xh, const float* __restrict__ a_s,
                     const float* __restrict__ a_d, const float* __restrict__ eattr,
                     const int* __restrict__ offs, const int2* __restrict__ csr,
                     const float* __restrict__ la, const float* __restrict__ M2l,
                     const float* __restrict__ bias, __half* __restrict__ out)
{
  int wid  = (blockIdx.x*blockDim.x + threadIdx.x) >> 6;
  int lane = threadIdx.x & 63;
  int nw   = (gridDim.x*blockDim.x) >> 6;
  int h = lane >> 4;
  float m2a = M2l[h], m2b = M2l[4+h];
  for (int n = wid; n < NNODES; n += nw){
    float asn = a_s[n*4+h];
    float adn = a_d[n*4+h];
    float al = lrelu(asn + adn + la[2*n]*m2a + la[2*n+1]*m2b);
    float pl = __expf(al);
    float denom = pl;
    uint4 u0 = *reinterpret_cast<const uint4*>(xh + (size_t)n*512 + lane*8);
    __half2* x0 = reinterpret_cast<__half2*>(&u0);
    __half2 pl2 = __float2half2_rn(pl);
    __half2 acc0 = __hmul2(x0[0], pl2), acc1 = __hmul2(x0[1], pl2);
    __half2 acc2 = __hmul2(x0[2], pl2), acc3 = __hmul2(x0[3], pl2);
    int b0 = offs[n], b1 = offs[n+1];
    int2 seA = make_int2(0,0), seB = make_int2(0,0);
    uint4 uA = make_uint4(0,0,0,0), uB = make_uint4(0,0,0,0);
    if (b0 < b1){
      seA = csr[b0];
      uA = *reinterpret_cast<const uint4*>(xh + (size_t)seA.x*512 + lane*8);
    }
    if (b0+1 < b1){
      seB = csr[b0+1];
      uB = *reinterpret_cast<const uint4*>(xh + (size_t)seB.x*512 + lane*8);
    }
    for (int idx=b0; idx<b1; ++idx){
      int s = seA.x, e = seA.y; uint4 u = uA;
      seA = seB; uA = uB;
      if (idx+2 < b1){
        seB = csr[idx+2];
        uB = *reinterpret_cast<const uint4*>(xh + (size_t)seB.x*512 + lane*8);
      }
      float2 ea = *reinterpret_cast<const float2*>(&eattr[2*e]);
      float al_e = lrelu(a_s[s*4+h] + adn + ea.x*m2a + ea.y*m2b);
      float pe = __expf(al_e);
      denom += pe;
      __half2 pe2 = __float2half2_rn(pe);
      __half2* y = reinterpret_cast<__half2*>(&u);
      acc0 = __hfma2(y[0], pe2, acc0);
      acc1 = __hfma2(y[1], pe2, acc1);
      acc2 = __hfma2(y[2], pe2, acc2);
      acc3 = __hfma2(y[3], pe2, acc3);
    }
    float sc = 0.25f/denom;
    float a[8];
    a[0]=__low2float(acc0); a[1]=__high2float(acc0);
    a[2]=__low2float(acc1); a[3]=__high2float(acc1);
    a[4]=__low2float(acc2); a[5]=__high2float(acc2);
    a[6]=__low2float(acc3); a[7]=__high2float(acc3);
    #pragma unroll
    for (int j=0;j<8;j++){
      a[j] *= sc;
      a[j] += __shfl_xor(a[j], 16);
      a[j] += __shfl_xor(a[j], 32);
    }
    if (lane < 16){
      int c = lane*8;
      float4 bb0 = *reinterpret_cast<const float4*>(&bias[c]);
      float4 bb1 = *reinterpret_cast<const float4*>(&bias[c+4]);
      __half2 hv[4];
      hv[0] = __floats2half2_rn(a[0]+bb0.x, a[1]+bb0.y);
      hv[1] = __floats2half2_rn(a[2]+bb0.z, a[3]+bb0.w);
      hv[2] = __floats2half2_rn(a[4]+bb1.x, a[5]+bb1.y);
      hv[3] = __floats2half2_rn(a[6]+bb1.z, a[7]+bb1.w);
      *reinterpret_cast<uint4*>(out + (size_t)n*128 + c) = *reinterpret_cast<uint4*>(hv);
    }
  }
}

// ---------------- graph norm (per-block partials, no atomics; f16 input) ----------------
__global__ __launch_bounds__(256) void k_colstat(const __half* __restrict__ X, float* __restrict__ part){
  int d = threadIdx.x & 127;
  int rg = threadIdx.x >> 7;
  float s1=0.f, s2=0.f;
  for (int n = blockIdx.x*2 + rg; n < NNODES; n += 512){
    float v = __half2float(X[(size_t)n*128 + d]);
    s1 += v; s2 = fmaf(v, v, s2);
  }
  __shared__ float sh[512];
  sh[threadIdx.x] = s1; sh[256+threadIdx.x] = s2;
  __syncthreads();
  if (threadIdx.x < 128){
    s1 = sh[threadIdx.x] + sh[threadIdx.x+128];
    s2 = sh[256+threadIdx.x] + sh[256+threadIdx.x+128];
    part[blockIdx.x*256 + d]       = s1;
    part[blockIdx.x*256 + 128 + d] = s2;
  }
}
__global__ __launch_bounds__(128) void k_finstat(const float* __restrict__ part,
                         const float* __restrict__ w, const float* __restrict__ b, const float* __restrict__ ms,
                         float* __restrict__ scaleA, float* __restrict__ shiftB){
  int d = threadIdx.x;
  float s1=0.f, s2=0.f;
  for (int bq=0; bq<256; bq++){ s1 += part[bq*256 + d]; s2 += part[bq*256 + 128 + d]; }
  float mean = s1 * (1.f/NNODES);
  float ex2  = s2 * (1.f/NNODES);
  float m = ms[d];
  float var = ex2 - m*mean*mean*(2.f - m);
  float sc = w[d] * rsqrtf(var + EPSV);
  scaleA[d] = sc;
  shiftB[d] = b[d] - sc*m*mean;
}
// norm + residual(bf16) + ELU; o is f16; write bf16 X (or f32 final output)
__global__ __launch_bounds__(256) void k_normelu(const __half* __restrict__ o, unsigned short* __restrict__ xb,
                         const float* __restrict__ scaleA, const float* __restrict__ shiftB,
                         float* __restrict__ fout){
  int i = blockIdx.x*256 + threadIdx.x;
  int stride = gridDim.x*256;
  for (; i < NNODES*32; i += stride){
    int d4 = i & 31;
    uint2 ou = ((const uint2*)o)[i];
    __half2* oh = reinterpret_cast<__half2*>(&ou);
    float o0 = __low2float(oh[0]), o1 = __high2float(oh[0]);
    float o2 = __low2float(oh[1]), o3 = __high2float(oh[1]);
    uint2 xu = ((const uint2*)xb)[i];
    float4 sc = ((const float4*)scaleA)[d4];
    float4 sh = ((const float4*)shiftB)[d4];
    float xi0 = __uint_as_float(xu.x<<16), xi1 = __uint_as_float(xu.x & 0xffff0000u);
    float xi2 = __uint_as_float(xu.y<<16), xi3 = __uint_as_float(xu.y & 0xffff0000u);
    float4 r; float y;
    y = fmaf(sc.x, o0, sh.x) + xi0; r.x = y > 0.f ? y : expm1f(y);
    y = fmaf(sc.y, o1, sh.y) + xi1; r.y = y > 0.f ? y : expm1f(y);
    y = fmaf(sc.z, o2, sh.z) + xi2; r.z = y > 0.f ? y : expm1f(y);
    y = fmaf(sc.w, o3, sh.w) + xi3; r.w = y > 0.f ? y : expm1f(y);
    if (fout){
      ((float4*)fout)[i] = r;
    } else {
      uint2 u; u.x = pk2(r.x, r.y); u.y = pk2(r.z, r.w);
      ((uint2*)xb)[i] = u;
    }
  }
}

// ---------------- host launch ----------------
extern "C" void kernel_launch(void* const* d_in, const int* in_sizes, int n_in,
                              void* d_out, int out_size, void* d_ws, size_t ws_size,
                              hipStream_t stream)
{
  const float* extra    = (const float*)d_in[0];
  const int*   ei       = (const int*)  d_in[1];
  const float* eattr    = (const float*)d_in[2];
  const int*   clus     = (const int*)  d_in[3];
  const float* user     = (const float*)d_in[4];
  const float* item     = (const float*)d_in[5];
  const float* W1       = (const float*)d_in[6];
  const float* b1       = (const float*)d_in[7];
  const float* W2       = (const float*)d_in[8];
  const float* b2       = (const float*)d_in[9];
  const float* gcnW     = (const float*)d_in[10];
  const float* gcnb     = (const float*)d_in[11];
  const float* g_lin    = (const float*)d_in[12];
  const float* g_lin_e  = (const float*)d_in[13];
  const float* g_att_s  = (const float*)d_in[14];
  const float* g_att_d  = (const float*)d_in[15];
  const float* g_att_e  = (const float*)d_in[16];
  const float* g_bias   = (const float*)d_in[17];
  const float* gat_lin  = (const float*)d_in[18];
  const float* gat_lin_e= (const float*)d_in[19];
  const float* gat_att_s= (const float*)d_in[20];
  const float* gat_att_d= (const float*)d_in[21];
  const float* gat_att_e= (const float*)d_in[22];
  const float* gat_bias = (const float*)d_in[23];
  const float* nw_      = (const float*)d_in[24];
  const float* nb_      = (const float*)d_in[25];
  const float* nms_     = (const float*)d_in[26];

  char* ws = (char*)d_ws;
  size_t off = 0;
  auto alloc = [&](size_t bytes)->char*{
    char* p = ws + off;
    off += (bytes + 255) & ~size_t(255);
    return p;
  };

  float* bufX = (float*)alloc((size_t)NNODES*128*4);
  float* bufY = (float*)alloc((size_t)NNODES*128*4);
  float* bufZ = (float*)alloc((size_t)NNODES*128*4);
  // shared "big" region (disjoint lifetimes):
  //   [0,20.5MB)    Xbf   (live from k_xcomb to end)
  //   [22,104MB)    XHf   (live during GAT layers only)
  //   [22,28.3MB)   pcb/pa0b/pa1b (pairhist phase, before MLP)
  //   [22,37.4MB)   Hbf   (MLP phase only)
  //   [40,53.1MB)   ppart (pool phase, before layers)
  char* big = alloc((size_t)112*1024*1024);
  unsigned short* Xbf   = (unsigned short*)big;
  unsigned short* XHf   = (unsigned short*)(big + (size_t)22*1024*1024);
  unsigned short* Hbf   = (unsigned short*)(big + (size_t)22*1024*1024);
  float* pcb  = (float*)(big + (size_t)22*1024*1024);
  float* pa0b = pcb  + 4096*128;
  float* pa1b = pa0b + 4096*128;
  float* ppart = (float*)(big + (size_t)40*1024*1024);
  int* offs   = (int*)alloc((NNODES+1)*4);
  int* ioffs  = (int*)alloc((NNODES+1)*4);
  int* bsum   = (int*)alloc(1024*4);
  int* bsum2  = (int*)alloc(1024*4);
  int2* csr   = (int2*)alloc((size_t)NEDGES*8);
  int* csr2   = (int*)alloc((size_t)NEDGES*4);
  float* a_s  = (float*)alloc((size_t)NNODES*4*4);
  float* a_d  = (float*)alloc((size_t)NNODES*4*4);
  float* la   = (float*)alloc((size_t)NNODES*2*4);
  // zeroed-per-call region (single memset)
  char* zero0 = ws + off;
  int*   cnt      = (int*)  alloc((size_t)NNODES*4);
  int*   intra    = (int*)  alloc((size_t)NNODES*4);
  int*   cursor   = (int*)  alloc((size_t)NNODES*4);
  int*   cursor2  = (int*)  alloc((size_t)NNODES*4);
  int*   csize    = (int*)  alloc(256*4);
  size_t zbytes = (size_t)((ws + off) - zero0);
  // small buffers
  float* pooled= (float*)alloc(8192*4);
  float* M2g   = (float*)alloc(8*4);
  float* M2    = (float*)alloc(24*4);
  float* pair_cnt = (float*)alloc(4096*4);
  float* avg_attr = (float*)alloc(8192*4);
  float* loop_c   = (float*)alloc(128*4);
  float* xh_c     = (float*)alloc(64*512*4);
  float* a_s_c    = (float*)alloc(256*4);
  float* a_d_c    = (float*)alloc(256*4);
  float* cl_out   = (float*)alloc(64*128*4);
  float* colpart  = (float*)alloc(256*256*4);
  float* scaleA   = (float*)alloc(128*4);
  float* shiftB   = (float*)alloc(128*4);
  unsigned short* W1t  = (unsigned short*)alloc((size_t)896*256*2);
  unsigned short* W2t  = (unsigned short*)alloc((size_t)256*128*2);
  unsigned short* gcnWt= (unsigned short*)alloc((size_t)128*128*2);
  unsigned short* glt  = (unsigned short*)alloc((size_t)3*128*512*2);
  if (off > ws_size) return;

  hipMemsetAsync(zero0, 0, zbytes, stream);

  const int NB = (NNODES+255)/256;
  // phase 0: pair hist + cnt/intra, reduce; dual scans; fill (CSR + intra-CSR); gather la
  k_pairhist<<<128, 1024, 0, stream>>>(ei, eattr, clus, cnt, intra, pcb, pa0b, pa1b);
  k_pairreduce<<<64, 64, 0, stream>>>(pcb, pa0b, pa1b, pair_cnt, avg_attr);
  k_scan_block<<<NB, 256, 0, stream>>>(cnt, offs, bsum, NNODES, clus, csize);
  k_scan_block<<<NB, 256, 0, stream>>>(intra, ioffs, bsum2, NNODES, nullptr, nullptr);
  k_scan_bsum<<<1, 512, 0, stream>>>(bsum, NB);
  k_scan_bsum<<<1, 512, 0, stream>>>(bsum2, NB);
  k_scan_add<<<NB, 256, 0, stream>>>(offs, bsum, NNODES, NEDGES);
  k_scan_add<<<NB, 256, 0, stream>>>(ioffs, bsum2, NNODES, 0);
  k_fill_csr<<<(NEDGES+255)/256, 256, 0, stream>>>(ei, clus, offs, ioffs, cursor, cursor2, csr, csr2);
  k_loopattr<<<NB, 256, 0, stream>>>(offs, csr, eattr, la);

  // small precomputes + weight conversions
  k_m2<<<1, 64, 0, stream>>>(g_lin_e, g_att_e, gat_lin_e, gat_att_e, M2g, M2);
  k_wtall<<<(475136+255)/256, 256, 0, stream>>>(W1, W2, gcnW, gat_lin, W1t, W2t, gcnWt, glt);

  // enrichment MLP (bf16 MFMA, f32-A fused conversion); Hbf reuses dead pairhist region
  {
    dim3 g1((N_ITEMS+127)/128, 2);
    k_mgemm<1,1,1,1,1,0><<<g1, 256, 0, stream>>>((const void*)item, extra, W1t, b1, (void*)Hbf,
                                                 N_ITEMS, 256, 896, 128, nullptr, nullptr, nullptr, nullptr);
    dim3 g2((N_ITEMS+127)/128, 1);
    k_mgemm<0,0,0,0,1,0><<<g2, 256, 0, stream>>>((const void*)Hbf, nullptr, W2t, b2,
                                                 (void*)(bufX + (size_t)N_USERS*128),
                                                 N_ITEMS, 128, 256, 0, nullptr, nullptr, nullptr, nullptr);
  }
  hipMemcpyAsync(bufX, user, (size_t)N_USERS*128*4, hipMemcpyDeviceToDevice, stream);

  // cluster GCN: XW (f16) = X @ gcnW; aggregate over intra-CSR only
  {
    dim3 g3((NNODES+127)/128, 1);
    k_mgemm<1,0,2,0,0,0><<<g3, 256, 0, stream>>>((const void*)bufX, nullptr, gcnWt, nullptr, (void*)bufY,
                                                 NNODES, 128, 128, 0, nullptr, nullptr, nullptr, nullptr);
  }
  k_gcn<<<5000, 256, 0, stream>>>((const unsigned short*)bufY, ioffs, csr2, intra, gcnb, bufZ);

  // pooling (LDS partials) + cluster GAT
  k_pool1<<<400, 256, 0, stream>>>(bufZ, clus, ppart);
  k_pool2<<<32, 256, 0, stream>>>(ppart, csize, pooled);
  {
    dim3 g4(1, 4);
    k_sgemm<0,0><<<g4, 256, 0, stream>>>(pooled, nullptr, g_lin, nullptr, xh_c, 64, 512, 128, 0);
  }
  k_loop_c<<<1, 64, 0, stream>>>(pair_cnt, avg_attr, loop_c);
  k_asc<<<1, 256, 0, stream>>>(xh_c, g_att_s, g_att_d, a_s_c, a_d_c);
  k_clout<<<64, 128, 0, stream>>>(a_s_c, a_d_c, loop_c, M2g, pair_cnt, avg_attr, xh_c, g_bias, cl_out);
  k_xcomb<<<1280, 256, 0, stream>>>(bufZ, cl_out, clus, Xbf);

  // 3 GAT layers (X in Xbf bf16; xh in f16; a_s/a_d fused in GEMM epilogue)
  for (int l = 0; l < 3; ++l){
    dim3 gx((NNODES+127)/128, 4);
    k_mgemm<0,0,2,0,0,1><<<gx, 256, 0, stream>>>((const void*)Xbf, nullptr, glt + (size_t)l*65536, nullptr,
                                                 (void*)XHf, NNODES, 512, 128, 0,
                                                 gat_att_s + l*512, gat_att_d + l*512, a_s, a_d);
    k_gat<<<20000, 256, 0, stream>>>(XHf, a_s, a_d, eattr, offs, csr, la,
                                     M2 + l*8, gat_bias + l*128, (__half*)bufY);
    k_colstat<<<256, 256, 0, stream>>>((const __half*)bufY, colpart);
    k_finstat<<<1, 128, 0, stream>>>(colpart, nw_ + l*128, nb_ + l*128, nms_ + l*128, scaleA, shiftB);
    k_normelu<<<1280, 256, 0, stream>>>((const __half*)bufY, Xbf, scaleA, shiftB, (l==2) ? (float*)d_out : nullptr);
  }
}